// Round 8
// baseline (306.994 us; speedup 1.0000x reference)
//
#include <hip/hip_runtime.h>
#include <math.h>

#define CHUNKS 16
#define LCH    128   // L / CHUNKS

// MFMA GEMM tile
#define TBM 128
#define TBN 64
#define TBK 32
#define LDT 40       // padded LDS row stride in ushorts (80 B, 16B-aligned)

typedef __attribute__((ext_vector_type(8))) short bf16x8;
typedef __attribute__((ext_vector_type(4))) float f32x4;
typedef __attribute__((ext_vector_type(8))) unsigned short us8;
typedef __attribute__((ext_vector_type(4))) unsigned short us4;

__device__ __forceinline__ unsigned short f2bf(float f) {
    unsigned int u = __float_as_uint(f);
    unsigned int r = (u + 0x7FFFu + ((u >> 16) & 1u)) >> 16;   // RNE
    return (unsigned short)r;
}

// ---------------- conversions ----------------
__global__ __launch_bounds__(256) void convert_bf16(
    const float* __restrict__ in, unsigned short* __restrict__ out, int n4)
{
    int i = blockIdx.x * 256 + threadIdx.x;
    if (i < n4) {
        float4 v = ((const float4*)in)[i];
        us4 u;
        u[0] = f2bf(v.x); u[1] = f2bf(v.y); u[2] = f2bf(v.z); u[3] = f2bf(v.w);
        ((us4*)out)[i] = u;
    }
}

// W[k][n] f32 -> Wt[n][k] bf16, 64x64 tiles via LDS
__global__ __launch_bounds__(256) void transpose_bf16(
    const float* __restrict__ W, unsigned short* __restrict__ Wt, int D)
{
    __shared__ float Ls[64][65];
    const int n0 = blockIdx.x * 64;
    const int k0 = blockIdx.y * 64;
    const int tx = threadIdx.x;

#pragma unroll
    for (int i = 0; i < 4; i++) {
        int idx = tx + i * 256;
        int kr = idx >> 4;
        int ng = idx & 15;
        float4 v = *(const float4*)&W[(size_t)(k0 + kr) * D + n0 + ng * 4];
        Ls[kr][ng * 4 + 0] = v.x;
        Ls[kr][ng * 4 + 1] = v.y;
        Ls[kr][ng * 4 + 2] = v.z;
        Ls[kr][ng * 4 + 3] = v.w;
    }
    __syncthreads();
#pragma unroll
    for (int i = 0; i < 4; i++) {
        int idx = tx + i * 256;
        int nr = idx >> 4;
        int kg = idx & 15;
        us4 u;
#pragma unroll
        for (int j = 0; j < 4; j++) u[j] = f2bf(Ls[kg * 4 + j][nr]);
        *(us4*)&Wt[(size_t)(n0 + nr) * D + k0 + kg * 4] = u;
    }
}

// ---------------- fused triple projection (transposed output) ----------------
// A-operand = Wt_i [D][K] bf16, B-operand = xbf [M][K] bf16.
// o_i[d][m] = sum_k Wt_i[d][k] * x[m][k]  (i.e. (x@W_i)^T), bias per d-row.
// o0 = sigmoid (z), o1 = none (x_ssm), o2 = softplus (dt).
__global__ __launch_bounds__(256) void proj3_mfma(
    const unsigned short* __restrict__ xbf,
    const unsigned short* __restrict__ W0t, const unsigned short* __restrict__ W1t,
    const unsigned short* __restrict__ W2t,
    const float* __restrict__ b0, const float* __restrict__ b1,
    const float* __restrict__ b2,
    float* __restrict__ o0, float* __restrict__ o1, float* __restrict__ o2,
    int M, int K, int D)
{
    __shared__ unsigned short As[3][TBM][LDT];
    __shared__ unsigned short Bs[TBN][LDT];

    const int tx = threadIdx.x;
    const int wave = tx >> 6;
    const int lane = tx & 63;
    const int wr = wave >> 1;        // 0..1 : d half (64 rows)
    const int wc = wave & 1;         // 0..1 : m half (32 cols)
    const int lrow = lane & 15;
    const int lk = lane >> 4;        // 0..3
    const int brow = blockIdx.y * TBM;   // d base
    const int bcol = blockIdx.x * TBN;   // m base

    const unsigned short* Wt[3] = {W0t, W1t, W2t};

    f32x4 acc[3][4][2];
#pragma unroll
    for (int w = 0; w < 3; w++)
#pragma unroll
        for (int m = 0; m < 4; m++)
#pragma unroll
            for (int n = 0; n < 2; n++) acc[w][m][n] = (f32x4)(0.f);

    for (int k0 = 0; k0 < K; k0 += TBK) {
        // stage A (3 weights): each 128x32 shorts = 512 us8, 2/thread
#pragma unroll
        for (int w = 0; w < 3; w++) {
#pragma unroll
            for (int i = 0; i < 2; i++) {
                int idx = tx + i * 256;
                int r = idx >> 2;
                int q = idx & 3;
                *(us8*)&As[w][r][q * 8] =
                    *(const us8*)&Wt[w][(size_t)(brow + r) * K + k0 + q * 8];
            }
        }
        // stage B (x): 64x32 shorts = 256 us8, 1/thread
        {
            int c = tx >> 2;
            int q = tx & 3;
            *(us8*)&Bs[c][q * 8] =
                *(const us8*)&xbf[(size_t)(bcol + c) * K + k0 + q * 8];
        }
        __syncthreads();

        bf16x8 av[3][4], bv[2];
#pragma unroll
        for (int w = 0; w < 3; w++)
#pragma unroll
            for (int m = 0; m < 4; m++)
                av[w][m] = *(const bf16x8*)&As[w][wr * 64 + m * 16 + lrow][lk * 8];
#pragma unroll
        for (int n = 0; n < 2; n++)
            bv[n] = *(const bf16x8*)&Bs[wc * 32 + n * 16 + lrow][lk * 8];
#pragma unroll
        for (int w = 0; w < 3; w++)
#pragma unroll
            for (int m = 0; m < 4; m++)
#pragma unroll
                for (int n = 0; n < 2; n++)
                    acc[w][m][n] = __builtin_amdgcn_mfma_f32_16x16x32_bf16(
                        av[w][m], bv[n], acc[w][m][n], 0, 0, 0);
        __syncthreads();
    }

    float* outp[3] = {o0, o1, o2};
    const float* biasp[3] = {b0, b1, b2};
#pragma unroll
    for (int w = 0; w < 3; w++) {
#pragma unroll
        for (int n = 0; n < 2; n++) {
            int col = bcol + wc * 32 + n * 16 + lrow;       // m index
#pragma unroll
            for (int m = 0; m < 4; m++) {
#pragma unroll
                for (int r = 0; r < 4; r++) {
                    int row = brow + wr * 64 + m * 16 + lk * 4 + r;   // d index
                    float v = acc[w][m][n][r] + biasp[w][row];
                    if (w == 0) v = 1.f / (1.f + __expf(-v));
                    else if (w == 2) v = (v > 20.f) ? v : log1pf(__expf(v));
                    outp[w][(size_t)row * M + col] = v;
                }
            }
        }
    }
}

// ---------------- bf16 MFMA GEMM (final projection, normal layout) ----------
__global__ __launch_bounds__(256) void gemm_mfma(
    const unsigned short* __restrict__ Abf, const unsigned short* __restrict__ Wt,
    const float* __restrict__ bias, float* __restrict__ out,
    int M, int K, int Nc)
{
    __shared__ unsigned short As[TBM][LDT];
    __shared__ unsigned short Bs[TBN][LDT];

    const int tx = threadIdx.x;
    const int wave = tx >> 6;
    const int lane = tx & 63;
    const int wr = wave >> 1;
    const int wc = wave & 1;
    const int lrow = lane & 15;
    const int lk = lane >> 4;
    const int brow = blockIdx.y * TBM;
    const int bcol = blockIdx.x * TBN;

    f32x4 acc[4][2];
#pragma unroll
    for (int m = 0; m < 4; m++)
#pragma unroll
        for (int n = 0; n < 2; n++) acc[m][n] = (f32x4)(0.f);

    for (int k0 = 0; k0 < K; k0 += TBK) {
#pragma unroll
        for (int i = 0; i < 2; i++) {
            int idx = tx + i * 256;
            int r = idx >> 2;
            int q = idx & 3;
            *(us8*)&As[r][q * 8] =
                *(const us8*)&Abf[(size_t)(brow + r) * K + k0 + q * 8];
        }
        {
            int c = tx >> 2;
            int q = tx & 3;
            *(us8*)&Bs[c][q * 8] =
                *(const us8*)&Wt[(size_t)(bcol + c) * K + k0 + q * 8];
        }
        __syncthreads();

        bf16x8 av[4], bv[2];
#pragma unroll
        for (int m = 0; m < 4; m++)
            av[m] = *(const bf16x8*)&As[wr * 64 + m * 16 + lrow][lk * 8];
#pragma unroll
        for (int n = 0; n < 2; n++)
            bv[n] = *(const bf16x8*)&Bs[wc * 32 + n * 16 + lrow][lk * 8];
#pragma unroll
        for (int m = 0; m < 4; m++)
#pragma unroll
            for (int n = 0; n < 2; n++)
                acc[m][n] = __builtin_amdgcn_mfma_f32_16x16x32_bf16(
                    av[m], bv[n], acc[m][n], 0, 0, 0);
        __syncthreads();
    }

#pragma unroll
    for (int n = 0; n < 2; n++) {
        int col = bcol + wc * 32 + n * 16 + lrow;
        float bval = bias[col];
#pragma unroll
        for (int m = 0; m < 4; m++) {
#pragma unroll
            for (int r = 0; r < 4; r++) {
                int row = brow + wr * 64 + m * 16 + lk * 4 + r;
                out[(size_t)row * Nc + col] = acc[m][n][r] + bval;
            }
        }
    }
}

// ---------------- fused B+C projection (transposed output) ----------------
// BCt[32][M]: rows 0..15 = Bm^T, rows 16..31 = C^T.
__global__ __launch_bounds__(256) void bc_proj(
    const float* __restrict__ x,
    const float* __restrict__ WB, const float* __restrict__ bB,
    const float* __restrict__ WC, const float* __restrict__ bC,
    float* __restrict__ BCt, int K, int M)
{
    __shared__ unsigned short Wl[32 * 1024];   // 64 KB

    const int tx = threadIdx.x;

#pragma unroll
    for (int i = 0; i < 16; i++) {
        int e = tx + i * 256;
        int k = e >> 2;
        int n0 = (e & 3) * 4;
        float4 v = ((const float4*)WB)[e];
        float vv[4] = {v.x, v.y, v.z, v.w};
#pragma unroll
        for (int j = 0; j < 4; j++) {
            int n = n0 + j;
            Wl[n * 1024 + (((k & ~7) ^ ((n & 15) << 3)) | (k & 7))] = f2bf(vv[j]);
        }
    }
#pragma unroll
    for (int i = 0; i < 16; i++) {
        int e = tx + i * 256;
        int k = e >> 2;
        int n0 = (e & 3) * 4;
        float4 v = ((const float4*)WC)[e];
        float vv[4] = {v.x, v.y, v.z, v.w};
#pragma unroll
        for (int j = 0; j < 4; j++) {
            int n = 16 + n0 + j;
            Wl[n * 1024 + (((k & ~7) ^ ((n & 15) << 3)) | (k & 7))] = f2bf(vv[j]);
        }
    }
    __syncthreads();

    const int n = tx & 31;
    const int r = tx >> 5;
    const int row = blockIdx.x * 8 + r;

    const unsigned short* wrow = &Wl[n * 1024];
    const int sw = (n & 15) << 3;
    const float* xrow = &x[(size_t)row * K];

    float acc = 0.f;
    for (int kb = 0; kb < K; kb += 8) {
        us8 w8 = *(const us8*)&wrow[kb ^ sw];
        float4 xa = *(const float4*)&xrow[kb];
        float4 xb = *(const float4*)&xrow[kb + 4];
        float xv[8] = {xa.x, xa.y, xa.z, xa.w, xb.x, xb.y, xb.z, xb.w};
#pragma unroll
        for (int j = 0; j < 8; j++) {
            acc = fmaf(xv[j], __uint_as_float((unsigned)(unsigned short)w8[j] << 16), acc);
        }
    }

    float bias = (n < 16) ? bB[n] : bC[n - 16];
    BCt[(size_t)n * M + row] = acc + bias;
}

// ---------------- chunked scan (transposed operands) ----------------
// xsT/dtT: [D][M] f32, BCt: [32][M] f32. Per-thread streams contiguous in t.
__global__ __launch_bounds__(256) void scan_phase1(
    const float* __restrict__ xsT, const float* __restrict__ dtT,
    const float* __restrict__ BCt, const float* __restrict__ A_log,
    float* __restrict__ P, float* __restrict__ Hl,
    int L, int D, int M)
{
    const int n  = threadIdx.x & 15;
    const int dl = threadIdx.x >> 4;
    const int d  = blockIdx.x * 16 + dl;
    const int c  = blockIdx.y;
    const int b  = blockIdx.z;

    const float Aval = -expf(A_log[d * 16 + n]);

    const size_t base  = (size_t)d * M + (size_t)b * L + (size_t)c * LCH;
    const size_t baseB = (size_t)n * M + (size_t)b * L + (size_t)c * LCH;

    float h = 0.f, p = 1.f;

    f32x4 dt4 = *(const f32x4*)&dtT[base];
    f32x4 xs4 = *(const f32x4*)&xsT[base];
    f32x4 bm4 = *(const f32x4*)&BCt[baseB];

    for (int t = 0; t < LCH; t += 4) {
        f32x4 dtn, xsn, bmn;
        if (t + 4 < LCH) {
            dtn = *(const f32x4*)&dtT[base + t + 4];
            xsn = *(const f32x4*)&xsT[base + t + 4];
            bmn = *(const f32x4*)&BCt[baseB + t + 4];
        }
#pragma unroll
        for (int j = 0; j < 4; j++) {
            float a = __expf(dt4[j] * Aval);
            h = fmaf(a, h, xs4[j] * dt4[j] * bm4[j]);
            p *= a;
        }
        dt4 = dtn; xs4 = xsn; bm4 = bmn;
    }

    size_t idx = (((size_t)b * D + d) * CHUNKS + c) * 16 + n;
    P[idx]  = p;
    Hl[idx] = h;
}

__global__ __launch_bounds__(256) void scan_phase2(
    const float* __restrict__ P, float* __restrict__ Hl, int D, int N)
{
    const int tid = blockIdx.x * 256 + threadIdx.x;   // over B*D*N
    const int n = tid & 15;
    const int d = (tid >> 4) & 1023;
    const int b = tid >> 14;

    size_t base = (((size_t)b * D + d) * CHUNKS) * N + n;

    float p[CHUNKS], hl[CHUNKS];
#pragma unroll
    for (int c = 0; c < CHUNKS; c++) {
        p[c]  = P[base + (size_t)c * N];
        hl[c] = Hl[base + (size_t)c * N];
    }
    float run = 0.f;
#pragma unroll
    for (int c = 0; c < CHUNKS; c++) {
        float tmp = hl[c];
        Hl[base + (size_t)c * N] = run;
        run = fmaf(p[c], run, tmp);
    }
}

// Phase 3: re-run chunk from carry-in; reduce h*C over 16-lane group; gate
// with z; write y DIRECTLY as bf16 in [M][D] layout (A-operand of final GEMM).
__global__ __launch_bounds__(256) void scan_phase3(
    const float* __restrict__ xsT, const float* __restrict__ dtT,
    const float* __restrict__ BCt, const float* __restrict__ zT,
    const float* __restrict__ A_log, const float* __restrict__ Hin,
    unsigned short* __restrict__ ybf, int L, int D, int M)
{
    const int n  = threadIdx.x & 15;
    const int dl = threadIdx.x >> 4;
    const int d  = blockIdx.x * 16 + dl;
    const int c  = blockIdx.y;
    const int b  = blockIdx.z;

    const float Aval = -expf(A_log[d * 16 + n]);

    const size_t base  = (size_t)d * M + (size_t)b * L + (size_t)c * LCH;
    const size_t baseB = (size_t)n * M + (size_t)b * L + (size_t)c * LCH;
    const size_t baseC = baseB + (size_t)16 * M;

    float h = Hin[(((size_t)b * D + d) * CHUNKS + c) * 16 + n];

    f32x4 dt4 = *(const f32x4*)&dtT[base];
    f32x4 xs4 = *(const f32x4*)&xsT[base];
    f32x4 bm4 = *(const f32x4*)&BCt[baseB];
    f32x4 cm4 = *(const f32x4*)&BCt[baseC];
    f32x4 z4  = *(const f32x4*)&zT[base];

    const int mrow0 = b * L + c * LCH;

    for (int t = 0; t < LCH; t += 4) {
        f32x4 dtn, xsn, bmn, cmn, zn;
        if (t + 4 < LCH) {
            dtn = *(const f32x4*)&dtT[base + t + 4];
            xsn = *(const f32x4*)&xsT[base + t + 4];
            bmn = *(const f32x4*)&BCt[baseB + t + 4];
            cmn = *(const f32x4*)&BCt[baseC + t + 4];
            zn  = *(const f32x4*)&zT[base + t + 4];
        }
#pragma unroll
        for (int j = 0; j < 4; j++) {
            float a = __expf(dt4[j] * Aval);
            h = fmaf(a, h, xs4[j] * dt4[j] * bm4[j]);
            float contrib = h * cm4[j];
            contrib += __shfl_xor(contrib, 1);
            contrib += __shfl_xor(contrib, 2);
            contrib += __shfl_xor(contrib, 4);
            contrib += __shfl_xor(contrib, 8);
            if (n == 0) {
                ybf[(size_t)(mrow0 + t + j) * D + d] = f2bf(contrib * z4[j]);
            }
        }
        dt4 = dtn; xs4 = xsn; bm4 = bmn; cm4 = cmn; z4 = zn;
    }
}

extern "C" void kernel_launch(void* const* d_in, const int* in_sizes, int n_in,
                              void* d_out, int out_size, void* d_ws, size_t ws_size,
                              hipStream_t stream) {
    const float* x     = (const float*)d_in[0];
    const float* Wz    = (const float*)d_in[1];
    const float* bz    = (const float*)d_in[2];
    const float* Wx    = (const float*)d_in[3];
    const float* bx    = (const float*)d_in[4];
    const float* WB    = (const float*)d_in[5];
    const float* bB    = (const float*)d_in[6];
    const float* WC    = (const float*)d_in[7];
    const float* bC    = (const float*)d_in[8];
    const float* Wdt   = (const float*)d_in[9];
    const float* bdt   = (const float*)d_in[10];
    const float* A_log = (const float*)d_in[11];
    const float* Wout  = (const float*)d_in[12];
    const float* bout  = (const float*)d_in[13];
    float* out = (float*)d_out;

    const int Bb = 2, L = 2048, D = 1024, N = 16;
    const int M = Bb * L;            // 4096
    const size_t MD = (size_t)M * D; // 4M

    float* ws   = (float*)d_ws;
    float* xsT  = ws;                         // [D][M]
    float* dtT  = xsT + MD;                   // [D][M]
    float* BCt  = dtT + MD;                   // [32][M]
    float* Pb   = BCt + (size_t)32 * M;
    float* Hlb  = Pb  + (size_t)Bb * D * CHUNKS * N;
    unsigned short* xbf   = (unsigned short*)(Hlb + (size_t)Bb * D * CHUNKS * N);
    unsigned short* Wzt   = xbf + MD;          // xbf reused as ybf after proj3
    unsigned short* Wxt   = Wzt + (size_t)D * D;
    unsigned short* Wdtt  = Wxt + (size_t)D * D;
    unsigned short* Woutt = Wdtt + (size_t)D * D;
    float* zT = out;   // z^T staged in d_out; fully overwritten by final GEMM

    dim3 blk(256);
    dim3 gridT(D / 64, D / 64);             // transpose tiles
    dim3 gridP3(M / TBN, D / TBM);          // (64, 8) fused projection
    dim3 gridOut(D / TBN, M / TBM);         // (16, 32) final GEMM

    convert_bf16<<<dim3((unsigned)(MD / 4 / 256)), blk, 0, stream>>>(x, xbf, (int)(MD / 4));
    transpose_bf16<<<gridT, blk, 0, stream>>>(Wz,   Wzt,   D);
    transpose_bf16<<<gridT, blk, 0, stream>>>(Wx,   Wxt,   D);
    transpose_bf16<<<gridT, blk, 0, stream>>>(Wdt,  Wdtt,  D);
    transpose_bf16<<<gridT, blk, 0, stream>>>(Wout, Woutt, D);

    // fused z / x_ssm / dt projection, transposed outputs
    proj3_mfma<<<gridP3, blk, 0, stream>>>(xbf, Wzt, Wxt, Wdtt, bz, bx, bdt,
                                           zT, xsT, dtT, M, D, D);
    bc_proj<<<dim3(M / 8), blk, 0, stream>>>(x, WB, bB, WC, bC, BCt, D, M);

    // chunked scan
    dim3 gridScan(D / 16, CHUNKS, Bb);
    scan_phase1<<<gridScan, blk, 0, stream>>>(xsT, dtT, BCt, A_log, Pb, Hlb, L, D, M);
    scan_phase2<<<dim3(Bb * D * N / 256), blk, 0, stream>>>(Pb, Hlb, D, N);
    scan_phase3<<<gridScan, blk, 0, stream>>>(xsT, dtT, BCt, zT, A_log, Hlb,
                                              xbf /* ybf */, L, D, M);

    // output projection (reads ybf in-place of xbf)
    gemm_mfma<<<gridOut, blk, 0, stream>>>(xbf, Woutt, bout, out, M, D, D);
}

// Round 10
// 292.393 us; speedup vs baseline: 1.0499x; 1.0499x over previous
//
#include <hip/hip_runtime.h>
#include <math.h>

#define CHUNKS 16
#define LCH    128   // L / CHUNKS

// m97-style MFMA GEMM tile
#define GBM 128
#define GBN 64
#define GBK 32

typedef __attribute__((ext_vector_type(8))) short bf16x8;
typedef __attribute__((ext_vector_type(4))) float f32x4;
typedef __attribute__((ext_vector_type(8))) unsigned short us8;
typedef __attribute__((ext_vector_type(4))) unsigned short us4;

typedef __attribute__((address_space(1))) const unsigned int gu32;
typedef __attribute__((address_space(3))) unsigned int lu32;

__device__ __forceinline__ void gload16(const unsigned short* g, unsigned short* l) {
    // async global->LDS, 16B per lane; LDS dest = uniform base + lane*16
    __builtin_amdgcn_global_load_lds((gu32*)g, (lu32*)l, 16, 0, 0);
}

__device__ __forceinline__ unsigned short f2bf(float f) {
    unsigned int u = __float_as_uint(f);
    unsigned int r = (u + 0x7FFFu + ((u >> 16) & 1u)) >> 16;   // RNE
    return (unsigned short)r;
}

// ---------------- conversions ----------------
__global__ __launch_bounds__(256) void convert_bf16(
    const float* __restrict__ in, unsigned short* __restrict__ out, int n4)
{
    int i = blockIdx.x * 256 + threadIdx.x;
    if (i < n4) {
        float4 v = ((const float4*)in)[i];
        us4 u;
        u[0] = f2bf(v.x); u[1] = f2bf(v.y); u[2] = f2bf(v.z); u[3] = f2bf(v.w);
        ((us4*)out)[i] = u;
    }
}

// 4 weight transposes in one dispatch: W[k][n] f32 -> Wt[n][k] bf16
__global__ __launch_bounds__(256) void transpose4_bf16(
    const float* __restrict__ W0, const float* __restrict__ W1,
    const float* __restrict__ W2, const float* __restrict__ W3,
    unsigned short* __restrict__ T0, unsigned short* __restrict__ T1,
    unsigned short* __restrict__ T2, unsigned short* __restrict__ T3, int D)
{
    const float* W = (blockIdx.z == 0) ? W0 : (blockIdx.z == 1) ? W1
                   : (blockIdx.z == 2) ? W2 : W3;
    unsigned short* Wt = (blockIdx.z == 0) ? T0 : (blockIdx.z == 1) ? T1
                       : (blockIdx.z == 2) ? T2 : T3;

    __shared__ float Ls[64][65];
    const int n0 = blockIdx.x * 64;
    const int k0 = blockIdx.y * 64;
    const int tx = threadIdx.x;

#pragma unroll
    for (int i = 0; i < 4; i++) {
        int idx = tx + i * 256;
        int kr = idx >> 4;
        int ng = idx & 15;
        float4 v = *(const float4*)&W[(size_t)(k0 + kr) * D + n0 + ng * 4];
        Ls[kr][ng * 4 + 0] = v.x;
        Ls[kr][ng * 4 + 1] = v.y;
        Ls[kr][ng * 4 + 2] = v.z;
        Ls[kr][ng * 4 + 3] = v.w;
    }
    __syncthreads();
#pragma unroll
    for (int i = 0; i < 4; i++) {
        int idx = tx + i * 256;
        int nr = idx >> 4;
        int kg = idx & 15;
        us4 u;
#pragma unroll
        for (int j = 0; j < 4; j++) u[j] = f2bf(Ls[kg * 4 + j][nr]);
        *(us4*)&Wt[(size_t)(n0 + nr) * D + k0 + kg * 4] = u;
    }
}

// ---------------- bf16 MFMA GEMM, m97 structure ----------------
// out[ra][rb] = sum_k A[ra][k]*B[rb][k]  (both operands row-major [rows][K] bf16)
// Tile 128(ra) x 64(rb) x 32(k); 4 waves 2x2; global_load_lds width-16 staging
// into LINEAR LDS; 8 MFMA + 6 ds_read_b128 per wave per K-step.
// mode: 0 none, 1 sigmoid, 2 softplus.  bias indexed by row (ra) or col (rb).
__global__ __launch_bounds__(256) void gemm_bt(
    const unsigned short* __restrict__ A, const unsigned short* __restrict__ B,
    const float* __restrict__ bias, float* __restrict__ out,
    int K, int ldo, int mode, int bias_by_row)
{
    __shared__ unsigned short As[GBM * GBK];   // 8 KB, 64 B per row
    __shared__ unsigned short Bs[GBN * GBK];   // 4 KB

    const int tx = threadIdx.x;
    const int wave = tx >> 6;
    const int lane = tx & 63;
    const int wr = wave >> 1;          // row half (64 rows)
    const int wc = wave & 1;           // col half (32 cols)
    const int lrow = lane & 15;
    const int lk = lane >> 4;          // 0..3
    const int brow = blockIdx.y * GBM;
    const int bcol = blockIdx.x * GBN;

    const int srow = lane >> 2;        // staging: row within 16-row chunk
    const int sq   = (lane & 3) * 8;   // staging: ushort offset within 64B row

    f32x4 acc[4][2];
#pragma unroll
    for (int m = 0; m < 4; m++)
#pragma unroll
        for (int n = 0; n < 2; n++) acc[m][n] = (f32x4)(0.f);

    for (int k0 = 0; k0 < K; k0 += GBK) {
        // wave w stages A rows [w*32, w*32+32) and B rows [w*16, w*16+16)
        gload16(&A[(size_t)(brow + wave * 32      + srow) * K + k0 + sq],
                &As[(wave * 32) * GBK]);
        gload16(&A[(size_t)(brow + wave * 32 + 16 + srow) * K + k0 + sq],
                &As[(wave * 32 + 16) * GBK]);
        gload16(&B[(size_t)(bcol + wave * 16      + srow) * K + k0 + sq],
                &Bs[(wave * 16) * GBK]);
        __syncthreads();

        bf16x8 av[4], bv[2];
#pragma unroll
        for (int m = 0; m < 4; m++)
            av[m] = *(const bf16x8*)&As[(wr * 64 + m * 16 + lrow) * GBK + lk * 8];
#pragma unroll
        for (int n = 0; n < 2; n++)
            bv[n] = *(const bf16x8*)&Bs[(wc * 32 + n * 16 + lrow) * GBK + lk * 8];
#pragma unroll
        for (int m = 0; m < 4; m++)
#pragma unroll
            for (int n = 0; n < 2; n++)
                acc[m][n] = __builtin_amdgcn_mfma_f32_16x16x32_bf16(
                    av[m], bv[n], acc[m][n], 0, 0, 0);
        __syncthreads();
    }

#pragma unroll
    for (int n = 0; n < 2; n++) {
        int col = bcol + wc * 32 + n * 16 + lrow;
        float bc = bias_by_row ? 0.f : bias[col];
#pragma unroll
        for (int m = 0; m < 4; m++) {
#pragma unroll
            for (int r = 0; r < 4; r++) {
                int row = brow + wr * 64 + m * 16 + lk * 4 + r;
                float v = acc[m][n][r] + (bias_by_row ? bias[row] : bc);
                if (mode == 1) v = 1.f / (1.f + __expf(-v));
                else if (mode == 2) v = (v > 20.f) ? v : log1pf(__expf(v));
                out[(size_t)row * ldo + col] = v;
            }
        }
    }
}

// ---------------- fused B+C projection (transposed output) ----------------
// BCt[32][M]: rows 0..15 = Bm^T, rows 16..31 = C^T.
__global__ __launch_bounds__(256) void bc_proj(
    const float* __restrict__ x,
    const float* __restrict__ WB, const float* __restrict__ bB,
    const float* __restrict__ WC, const float* __restrict__ bC,
    float* __restrict__ BCt, int K, int M)
{
    __shared__ unsigned short Wl[32 * 1024];   // 64 KB

    const int tx = threadIdx.x;

#pragma unroll
    for (int i = 0; i < 16; i++) {
        int e = tx + i * 256;
        int k = e >> 2;
        int n0 = (e & 3) * 4;
        float4 v = ((const float4*)WB)[e];
        float vv[4] = {v.x, v.y, v.z, v.w};
#pragma unroll
        for (int j = 0; j < 4; j++) {
            int n = n0 + j;
            Wl[n * 1024 + (((k & ~7) ^ ((n & 15) << 3)) | (k & 7))] = f2bf(vv[j]);
        }
    }
#pragma unroll
    for (int i = 0; i < 16; i++) {
        int e = tx + i * 256;
        int k = e >> 2;
        int n0 = (e & 3) * 4;
        float4 v = ((const float4*)WC)[e];
        float vv[4] = {v.x, v.y, v.z, v.w};
#pragma unroll
        for (int j = 0; j < 4; j++) {
            int n = 16 + n0 + j;
            Wl[n * 1024 + (((k & ~7) ^ ((n & 15) << 3)) | (k & 7))] = f2bf(vv[j]);
        }
    }
    __syncthreads();

    const int n = tx & 31;
    const int r = tx >> 5;
    const int row = blockIdx.x * 8 + r;

    const unsigned short* wrow = &Wl[n * 1024];
    const int sw = (n & 15) << 3;
    const float* xrow = &x[(size_t)row * K];

    float acc = 0.f;
    for (int kb = 0; kb < K; kb += 8) {
        us8 w8 = *(const us8*)&wrow[kb ^ sw];
        float4 xa = *(const float4*)&xrow[kb];
        float4 xb = *(const float4*)&xrow[kb + 4];
        float xv[8] = {xa.x, xa.y, xa.z, xa.w, xb.x, xb.y, xb.z, xb.w};
#pragma unroll
        for (int j = 0; j < 8; j++) {
            acc = fmaf(xv[j], __uint_as_float((unsigned)(unsigned short)w8[j] << 16), acc);
        }
    }

    float bias = (n < 16) ? bB[n] : bC[n - 16];
    BCt[(size_t)n * M + row] = acc + bias;
}

// ---------------- chunked scan (transposed operands) ----------------
// xsT/dtT: [D][M] f32, BCt: [32][M] f32. Per-thread streams contiguous in t.
__global__ __launch_bounds__(256) void scan_phase1(
    const float* __restrict__ xsT, const float* __restrict__ dtT,
    const float* __restrict__ BCt, const float* __restrict__ A_log,
    float* __restrict__ P, float* __restrict__ Hl,
    int L, int D, int M)
{
    const int n  = threadIdx.x & 15;
    const int dl = threadIdx.x >> 4;
    const int d  = blockIdx.x * 16 + dl;
    const int c  = blockIdx.y;
    const int b  = blockIdx.z;

    const float Aval = -expf(A_log[d * 16 + n]);

    const size_t base  = (size_t)d * M + (size_t)b * L + (size_t)c * LCH;
    const size_t baseB = (size_t)n * M + (size_t)b * L + (size_t)c * LCH;

    float h = 0.f, p = 1.f;

    f32x4 dt4 = *(const f32x4*)&dtT[base];
    f32x4 xs4 = *(const f32x4*)&xsT[base];
    f32x4 bm4 = *(const f32x4*)&BCt[baseB];

    for (int t = 0; t < LCH; t += 4) {
        f32x4 dtn, xsn, bmn;
        if (t + 4 < LCH) {
            dtn = *(const f32x4*)&dtT[base + t + 4];
            xsn = *(const f32x4*)&xsT[base + t + 4];
            bmn = *(const f32x4*)&BCt[baseB + t + 4];
        }
#pragma unroll
        for (int j = 0; j < 4; j++) {
            float a = __expf(dt4[j] * Aval);
            h = fmaf(a, h, xs4[j] * dt4[j] * bm4[j]);
            p *= a;
        }
        dt4 = dtn; xs4 = xsn; bm4 = bmn;
    }

    size_t idx = (((size_t)b * D + d) * CHUNKS + c) * 16 + n;
    P[idx]  = p;
    Hl[idx] = h;
}

__global__ __launch_bounds__(256) void scan_phase2(
    const float* __restrict__ P, float* __restrict__ Hl, int D, int N)
{
    const int tid = blockIdx.x * 256 + threadIdx.x;   // over B*D*N
    const int n = tid & 15;
    const int d = (tid >> 4) & 1023;
    const int b = tid >> 14;

    size_t base = (((size_t)b * D + d) * CHUNKS) * N + n;

    float p[CHUNKS], hl[CHUNKS];
#pragma unroll
    for (int c = 0; c < CHUNKS; c++) {
        p[c]  = P[base + (size_t)c * N];
        hl[c] = Hl[base + (size_t)c * N];
    }
    float run = 0.f;
#pragma unroll
    for (int c = 0; c < CHUNKS; c++) {
        float tmp = hl[c];
        Hl[base + (size_t)c * N] = run;
        run = fmaf(p[c], run, tmp);
    }
}

// Phase 3: re-run chunk from carry-in; reduce h*C over 16-lane group; gate
// with z; write y DIRECTLY as bf16 in [M][D] layout (A-operand of final GEMM).
__global__ __launch_bounds__(256) void scan_phase3(
    const float* __restrict__ xsT, const float* __restrict__ dtT,
    const float* __restrict__ BCt, const float* __restrict__ zT,
    const float* __restrict__ A_log, const float* __restrict__ Hin,
    unsigned short* __restrict__ ybf, int L, int D, int M)
{
    const int n  = threadIdx.x & 15;
    const int dl = threadIdx.x >> 4;
    const int d  = blockIdx.x * 16 + dl;
    const int c  = blockIdx.y;
    const int b  = blockIdx.z;

    const float Aval = -expf(A_log[d * 16 + n]);

    const size_t base  = (size_t)d * M + (size_t)b * L + (size_t)c * LCH;
    const size_t baseB = (size_t)n * M + (size_t)b * L + (size_t)c * LCH;
    const size_t baseC = baseB + (size_t)16 * M;

    float h = Hin[(((size_t)b * D + d) * CHUNKS + c) * 16 + n];

    f32x4 dt4 = *(const f32x4*)&dtT[base];
    f32x4 xs4 = *(const f32x4*)&xsT[base];
    f32x4 bm4 = *(const f32x4*)&BCt[baseB];
    f32x4 cm4 = *(const f32x4*)&BCt[baseC];
    f32x4 z4  = *(const f32x4*)&zT[base];

    const int mrow0 = b * L + c * LCH;

    for (int t = 0; t < LCH; t += 4) {
        f32x4 dtn, xsn, bmn, cmn, zn;
        if (t + 4 < LCH) {
            dtn = *(const f32x4*)&dtT[base + t + 4];
            xsn = *(const f32x4*)&xsT[base + t + 4];
            bmn = *(const f32x4*)&BCt[baseB + t + 4];
            cmn = *(const f32x4*)&BCt[baseC + t + 4];
            zn  = *(const f32x4*)&zT[base + t + 4];
        }
#pragma unroll
        for (int j = 0; j < 4; j++) {
            float a = __expf(dt4[j] * Aval);
            h = fmaf(a, h, xs4[j] * dt4[j] * bm4[j]);
            float contrib = h * cm4[j];
            contrib += __shfl_xor(contrib, 1);
            contrib += __shfl_xor(contrib, 2);
            contrib += __shfl_xor(contrib, 4);
            contrib += __shfl_xor(contrib, 8);
            if (n == 0) {
                ybf[(size_t)(mrow0 + t + j) * D + d] = f2bf(contrib * z4[j]);
            }
        }
        dt4 = dtn; xs4 = xsn; bm4 = bmn; cm4 = cmn; z4 = zn;
    }
}

extern "C" void kernel_launch(void* const* d_in, const int* in_sizes, int n_in,
                              void* d_out, int out_size, void* d_ws, size_t ws_size,
                              hipStream_t stream) {
    const float* x     = (const float*)d_in[0];
    const float* Wz    = (const float*)d_in[1];
    const float* bz    = (const float*)d_in[2];
    const float* Wx    = (const float*)d_in[3];
    const float* bx    = (const float*)d_in[4];
    const float* WB    = (const float*)d_in[5];
    const float* bB    = (const float*)d_in[6];
    const float* WC    = (const float*)d_in[7];
    const float* bC    = (const float*)d_in[8];
    const float* Wdt   = (const float*)d_in[9];
    const float* bdt   = (const float*)d_in[10];
    const float* A_log = (const float*)d_in[11];
    const float* Wout  = (const float*)d_in[12];
    const float* bout  = (const float*)d_in[13];
    float* out = (float*)d_out;

    const int Bb = 2, L = 2048, D = 1024, N = 16;
    const int M = Bb * L;            // 4096
    const size_t MD = (size_t)M * D; // 4M

    float* ws   = (float*)d_ws;
    float* xsT  = ws;                         // [D][M]
    float* dtT  = xsT + MD;                   // [D][M]
    float* BCt  = dtT + MD;                   // [32][M]
    float* Pb   = BCt + (size_t)32 * M;
    float* Hlb  = Pb  + (size_t)Bb * D * CHUNKS * N;
    unsigned short* xbf   = (unsigned short*)(Hlb + (size_t)Bb * D * CHUNKS * N);
    unsigned short* Wzt   = xbf + MD;          // xbf reused as ybf after projections
    unsigned short* Wxt   = Wzt + (size_t)D * D;
    unsigned short* Wdtt  = Wxt + (size_t)D * D;
    unsigned short* Woutt = Wdtt + (size_t)D * D;
    float* zT = out;   // z^T staged in d_out; fully overwritten by final GEMM

    dim3 blk(256);
    dim3 gridT(D / 64, D / 64, 4);          // 4 transposes in one dispatch
    dim3 gridP(M / GBN, D / GBM);           // (64, 8) transposed projections
    dim3 gridOut(D / GBN, M / GBM);         // (16, 32) final GEMM

    convert_bf16<<<dim3((unsigned)(MD / 4 / 256)), blk, 0, stream>>>(x, xbf, (int)(MD / 4));
    transpose4_bf16<<<gridT, blk, 0, stream>>>(Wz, Wx, Wdt, Wout,
                                               Wzt, Wxt, Wdtt, Woutt, D);

    // projections: out^T[d][m], bias per row (d)
    gemm_bt<<<gridP, blk, 0, stream>>>(Wzt,  xbf, bz,  zT,  D, M, 1, 1);
    gemm_bt<<<gridP, blk, 0, stream>>>(Wxt,  xbf, bx,  xsT, D, M, 0, 1);
    gemm_bt<<<gridP, blk, 0, stream>>>(Wdtt, xbf, bdt, dtT, D, M, 2, 1);
    bc_proj<<<dim3(M / 8), blk, 0, stream>>>(x, WB, bB, WC, bC, BCt, D, M);

    // chunked scan
    dim3 gridScan(D / 16, CHUNKS, Bb);
    scan_phase1<<<gridScan, blk, 0, stream>>>(xsT, dtT, BCt, A_log, Pb, Hlb, L, D, M);
    scan_phase2<<<dim3(Bb * D * N / 256), blk, 0, stream>>>(Pb, Hlb, D, N);
    scan_phase3<<<gridScan, blk, 0, stream>>>(xsT, dtT, BCt, zT, A_log, Hlb,
                                              xbf /* ybf */, L, D, M);

    // output projection: out[m][d] = sum_k ybf[m][k]*Woutt[d][k], bias per col (d)
    gemm_bt<<<gridOut, blk, 0, stream>>>(xbf, Woutt, bout, out, D, D, 0, 0);
}

// Round 11
// 200.036 us; speedup vs baseline: 1.5347x; 1.4617x over previous
//
#include <hip/hip_runtime.h>
#include <math.h>

#define CHUNKS 64
#define LCH    32    // L / CHUNKS

// m97-style MFMA GEMM tile
#define GBM 128
#define GBN 64
#define GBK 32

typedef __attribute__((ext_vector_type(8))) short bf16x8;
typedef __attribute__((ext_vector_type(4))) float f32x4;
typedef __attribute__((ext_vector_type(8))) unsigned short us8;
typedef __attribute__((ext_vector_type(4))) unsigned short us4;

typedef __attribute__((address_space(1))) const unsigned int gu32;
typedef __attribute__((address_space(3))) unsigned int lu32;

__device__ __forceinline__ void gload16(const unsigned short* g, unsigned short* l) {
    // async global->LDS, 16B per lane; LDS dest = uniform base + lane*16
    __builtin_amdgcn_global_load_lds((gu32*)g, (lu32*)l, 16, 0, 0);
}

__device__ __forceinline__ unsigned short f2bf(float f) {
    unsigned int u = __float_as_uint(f);
    unsigned int r = (u + 0x7FFFu + ((u >> 16) & 1u)) >> 16;   // RNE
    return (unsigned short)r;
}

// ---------------- conversions ----------------
__global__ __launch_bounds__(256) void convert_bf16(
    const float* __restrict__ in, unsigned short* __restrict__ out, int n4)
{
    int i = blockIdx.x * 256 + threadIdx.x;
    if (i < n4) {
        float4 v = ((const float4*)in)[i];
        us4 u;
        u[0] = f2bf(v.x); u[1] = f2bf(v.y); u[2] = f2bf(v.z); u[3] = f2bf(v.w);
        ((us4*)out)[i] = u;
    }
}

// 4 weight transposes in one dispatch: W[k][n] f32 -> Wt[n][k] bf16
__global__ __launch_bounds__(256) void transpose4_bf16(
    const float* __restrict__ W0, const float* __restrict__ W1,
    const float* __restrict__ W2, const float* __restrict__ W3,
    unsigned short* __restrict__ T0, unsigned short* __restrict__ T1,
    unsigned short* __restrict__ T2, unsigned short* __restrict__ T3, int D)
{
    const float* W = (blockIdx.z == 0) ? W0 : (blockIdx.z == 1) ? W1
                   : (blockIdx.z == 2) ? W2 : W3;
    unsigned short* Wt = (blockIdx.z == 0) ? T0 : (blockIdx.z == 1) ? T1
                       : (blockIdx.z == 2) ? T2 : T3;

    __shared__ float Ls[64][65];
    const int n0 = blockIdx.x * 64;
    const int k0 = blockIdx.y * 64;
    const int tx = threadIdx.x;

#pragma unroll
    for (int i = 0; i < 4; i++) {
        int idx = tx + i * 256;
        int kr = idx >> 4;
        int ng = idx & 15;
        float4 v = *(const float4*)&W[(size_t)(k0 + kr) * D + n0 + ng * 4];
        Ls[kr][ng * 4 + 0] = v.x;
        Ls[kr][ng * 4 + 1] = v.y;
        Ls[kr][ng * 4 + 2] = v.z;
        Ls[kr][ng * 4 + 3] = v.w;
    }
    __syncthreads();
#pragma unroll
    for (int i = 0; i < 4; i++) {
        int idx = tx + i * 256;
        int nr = idx >> 4;
        int kg = idx & 15;
        us4 u;
#pragma unroll
        for (int j = 0; j < 4; j++) u[j] = f2bf(Ls[kg * 4 + j][nr]);
        *(us4*)&Wt[(size_t)(n0 + nr) * D + k0 + kg * 4] = u;
    }
}

// ---------------- bf16 MFMA GEMM, m97 structure ----------------
// out[ra][rb] = sum_k A[ra][k]*B[rb][k]  (both operands row-major [rows][K] bf16)
__global__ __launch_bounds__(256) void gemm_bt(
    const unsigned short* __restrict__ A, const unsigned short* __restrict__ B,
    const float* __restrict__ bias, float* __restrict__ out,
    int K, int ldo, int mode)
{
    __shared__ unsigned short As[GBM * GBK];   // 8 KB
    __shared__ unsigned short Bs[GBN * GBK];   // 4 KB

    const int tx = threadIdx.x;
    const int wave = tx >> 6;
    const int lane = tx & 63;
    const int wr = wave >> 1;
    const int wc = wave & 1;
    const int lrow = lane & 15;
    const int lk = lane >> 4;
    const int brow = blockIdx.y * GBM;
    const int bcol = blockIdx.x * GBN;

    const int srow = lane >> 2;
    const int sq   = (lane & 3) * 8;

    f32x4 acc[4][2];
#pragma unroll
    for (int m = 0; m < 4; m++)
#pragma unroll
        for (int n = 0; n < 2; n++) acc[m][n] = (f32x4)(0.f);

    for (int k0 = 0; k0 < K; k0 += GBK) {
        gload16(&A[(size_t)(brow + wave * 32      + srow) * K + k0 + sq],
                &As[(wave * 32) * GBK]);
        gload16(&A[(size_t)(brow + wave * 32 + 16 + srow) * K + k0 + sq],
                &As[(wave * 32 + 16) * GBK]);
        gload16(&B[(size_t)(bcol + wave * 16      + srow) * K + k0 + sq],
                &Bs[(wave * 16) * GBK]);
        __syncthreads();

        bf16x8 av[4], bv[2];
#pragma unroll
        for (int m = 0; m < 4; m++)
            av[m] = *(const bf16x8*)&As[(wr * 64 + m * 16 + lrow) * GBK + lk * 8];
#pragma unroll
        for (int n = 0; n < 2; n++)
            bv[n] = *(const bf16x8*)&Bs[(wc * 32 + n * 16 + lrow) * GBK + lk * 8];
#pragma unroll
        for (int m = 0; m < 4; m++)
#pragma unroll
            for (int n = 0; n < 2; n++)
                acc[m][n] = __builtin_amdgcn_mfma_f32_16x16x32_bf16(
                    av[m], bv[n], acc[m][n], 0, 0, 0);
        __syncthreads();
    }

#pragma unroll
    for (int n = 0; n < 2; n++) {
        int col = bcol + wc * 32 + n * 16 + lrow;
        float bval = bias[col];
#pragma unroll
        for (int m = 0; m < 4; m++) {
#pragma unroll
            for (int r = 0; r < 4; r++) {
                int row = brow + wr * 64 + m * 16 + lk * 4 + r;
                float v = acc[m][n][r] + bval;
                if (mode == 1) v = 1.f / (1.f + __expf(-v));
                else if (mode == 2) v = (v > 20.f) ? v : log1pf(__expf(v));
                out[(size_t)row * ldo + col] = v;
            }
        }
    }
}

// ---------------- fused B+C projection ----------------
// BC[m][32]: cols 0..15 = Bm, 16..31 = C.
__global__ __launch_bounds__(256) void bc_proj(
    const float* __restrict__ x,
    const float* __restrict__ WB, const float* __restrict__ bB,
    const float* __restrict__ WC, const float* __restrict__ bC,
    float* __restrict__ BC, int K, int M)
{
    __shared__ unsigned short Wl[32 * 1024];   // 64 KB

    const int tx = threadIdx.x;

#pragma unroll
    for (int i = 0; i < 16; i++) {
        int e = tx + i * 256;
        int k = e >> 2;
        int n0 = (e & 3) * 4;
        float4 v = ((const float4*)WB)[e];
        float vv[4] = {v.x, v.y, v.z, v.w};
#pragma unroll
        for (int j = 0; j < 4; j++) {
            int n = n0 + j;
            Wl[n * 1024 + (((k & ~7) ^ ((n & 15) << 3)) | (k & 7))] = f2bf(vv[j]);
        }
    }
#pragma unroll
    for (int i = 0; i < 16; i++) {
        int e = tx + i * 256;
        int k = e >> 2;
        int n0 = (e & 3) * 4;
        float4 v = ((const float4*)WC)[e];
        float vv[4] = {v.x, v.y, v.z, v.w};
#pragma unroll
        for (int j = 0; j < 4; j++) {
            int n = 16 + n0 + j;
            Wl[n * 1024 + (((k & ~7) ^ ((n & 15) << 3)) | (k & 7))] = f2bf(vv[j]);
        }
    }
    __syncthreads();

    const int n = tx & 31;
    const int r = tx >> 5;
    const int row = blockIdx.x * 8 + r;

    const unsigned short* wrow = &Wl[n * 1024];
    const int sw = (n & 15) << 3;
    const float* xrow = &x[(size_t)row * K];

    float acc = 0.f;
    for (int kb = 0; kb < K; kb += 8) {
        us8 w8 = *(const us8*)&wrow[kb ^ sw];
        float4 xa = *(const float4*)&xrow[kb];
        float4 xb = *(const float4*)&xrow[kb + 4];
        float xv[8] = {xa.x, xa.y, xa.z, xa.w, xb.x, xb.y, xb.z, xb.w};
#pragma unroll
        for (int j = 0; j < 8; j++) {
            acc = fmaf(xv[j], __uint_as_float((unsigned)(unsigned short)w8[j] << 16), acc);
        }
    }

    float bias = (n < 16) ? bB[n] : bC[n - 16];
    BC[(size_t)row * 32 + n] = acc + bias;
}

// ---------------- chunked scan: thread = one d, all 16 states in regs ------
// grid (D/256, CHUNKS, B), block 256. Operands in natural [M][D] layout.
__global__ __launch_bounds__(256) void scan_phase1(
    const float* __restrict__ xs, const float* __restrict__ dt,
    const float* __restrict__ BC, const float* __restrict__ A_log,
    float* __restrict__ P, float* __restrict__ Hl, int L, int D, int M)
{
    const int tx = threadIdx.x;
    const int d  = blockIdx.x * 256 + tx;
    const int c  = blockIdx.y;
    const int b  = blockIdx.z;
    const int m0 = b * L + c * LCH;

    __shared__ float bcs[LCH][32];
    {
        int row = tx >> 3, col = (tx & 7) * 4;
        *(f32x4*)&bcs[row][col] = *(const f32x4*)&BC[(size_t)(m0 + row) * 32 + col];
    }
    __syncthreads();

    float Av[16];
#pragma unroll
    for (int i = 0; i < 4; i++) {
        f32x4 a4 = *(const f32x4*)&A_log[d * 16 + i * 4];
#pragma unroll
        for (int j = 0; j < 4; j++) Av[i * 4 + j] = -__expf(a4[j]);
    }

    float h[16];
#pragma unroll
    for (int n = 0; n < 16; n++) h[n] = 0.f;
    float dts = 0.f;

    const size_t base = (size_t)m0 * D + d;
    float dtv = dt[base], xv = xs[base];
    for (int t = 0; t < LCH; t++) {
        float dtn = 0.f, xvn = 0.f;
        if (t + 1 < LCH) {
            dtn = dt[base + (size_t)(t + 1) * D];
            xvn = xs[base + (size_t)(t + 1) * D];
        }
        float xdt = xv * dtv;
        dts += dtv;
        f32x4 bm[4];
#pragma unroll
        for (int i = 0; i < 4; i++) bm[i] = *(const f32x4*)&bcs[t][i * 4];
#pragma unroll
        for (int n = 0; n < 16; n++) {
            float a = __expf(dtv * Av[n]);
            h[n] = fmaf(a, h[n], xdt * bm[n >> 2][n & 3]);
        }
        dtv = dtn; xv = xvn;
    }

    // decay product over chunk: prod exp(dt*A) = exp(A * sum dt)
    size_t idx = (((size_t)b * D + d) * CHUNKS + c) * 16;
#pragma unroll
    for (int i = 0; i < 4; i++) {
        f32x4 p4, h4;
#pragma unroll
        for (int j = 0; j < 4; j++) {
            p4[j] = __expf(Av[i * 4 + j] * dts);
            h4[j] = h[i * 4 + j];
        }
        *(f32x4*)&P[idx + i * 4]  = p4;
        *(f32x4*)&Hl[idx + i * 4] = h4;
    }
}

// serial scan over chunks per (b,d,n); overwrites Hl with carry-IN per chunk.
__global__ __launch_bounds__(256) void scan_phase2(
    const float* __restrict__ P, float* __restrict__ Hl, int D, int N)
{
    const int tid = blockIdx.x * 256 + threadIdx.x;   // B*D*N
    const int n = tid & 15;
    const int dd = (tid >> 4) & 1023;
    const int b = tid >> 14;

    size_t base = (((size_t)b * D + dd) * CHUNKS) * 16 + n;
    float run = 0.f;
#pragma unroll 4
    for (int c = 0; c < CHUNKS; c++) {
        float p   = P[base + (size_t)c * 16];
        float tmp = Hl[base + (size_t)c * 16];
        Hl[base + (size_t)c * 16] = run;
        run = fmaf(p, run, tmp);
    }
}

__global__ __launch_bounds__(256) void scan_phase3(
    const float* __restrict__ xs, const float* __restrict__ dt,
    const float* __restrict__ BC, const float* __restrict__ z,
    const float* __restrict__ A_log, const float* __restrict__ Hin,
    unsigned short* __restrict__ ybf, int L, int D, int M)
{
    const int tx = threadIdx.x;
    const int d  = blockIdx.x * 256 + tx;
    const int c  = blockIdx.y;
    const int b  = blockIdx.z;
    const int m0 = b * L + c * LCH;

    __shared__ float bcs[LCH][32];
    {
        int row = tx >> 3, col = (tx & 7) * 4;
        *(f32x4*)&bcs[row][col] = *(const f32x4*)&BC[(size_t)(m0 + row) * 32 + col];
    }
    __syncthreads();

    float Av[16];
#pragma unroll
    for (int i = 0; i < 4; i++) {
        f32x4 a4 = *(const f32x4*)&A_log[d * 16 + i * 4];
#pragma unroll
        for (int j = 0; j < 4; j++) Av[i * 4 + j] = -__expf(a4[j]);
    }

    float h[16];
    {
        size_t hidx = (((size_t)b * D + d) * CHUNKS + c) * 16;
#pragma unroll
        for (int i = 0; i < 4; i++) {
            f32x4 h4 = *(const f32x4*)&Hin[hidx + i * 4];
#pragma unroll
            for (int j = 0; j < 4; j++) h[i * 4 + j] = h4[j];
        }
    }

    const size_t base = (size_t)m0 * D + d;
    float dtv = dt[base], xv = xs[base], zv = z[base];
    for (int t = 0; t < LCH; t++) {
        float dtn = 0.f, xvn = 0.f, zvn = 0.f;
        if (t + 1 < LCH) {
            dtn = dt[base + (size_t)(t + 1) * D];
            xvn = xs[base + (size_t)(t + 1) * D];
            zvn = z[base + (size_t)(t + 1) * D];
        }
        float xdt = xv * dtv;
        f32x4 bm[4], cm[4];
#pragma unroll
        for (int i = 0; i < 4; i++) {
            bm[i] = *(const f32x4*)&bcs[t][i * 4];
            cm[i] = *(const f32x4*)&bcs[t][16 + i * 4];
        }
        float y = 0.f;
#pragma unroll
        for (int n = 0; n < 16; n++) {
            float a = __expf(dtv * Av[n]);
            h[n] = fmaf(a, h[n], xdt * bm[n >> 2][n & 3]);
            y = fmaf(h[n], cm[n >> 2][n & 3], y);
        }
        ybf[base + (size_t)t * D] = f2bf(y * zv);
        dtv = dtn; xv = xvn; zv = zvn;
    }
}

extern "C" void kernel_launch(void* const* d_in, const int* in_sizes, int n_in,
                              void* d_out, int out_size, void* d_ws, size_t ws_size,
                              hipStream_t stream) {
    const float* x     = (const float*)d_in[0];
    const float* Wz    = (const float*)d_in[1];
    const float* bz    = (const float*)d_in[2];
    const float* Wx    = (const float*)d_in[3];
    const float* bx    = (const float*)d_in[4];
    const float* WB    = (const float*)d_in[5];
    const float* bB    = (const float*)d_in[6];
    const float* WC    = (const float*)d_in[7];
    const float* bC    = (const float*)d_in[8];
    const float* Wdt   = (const float*)d_in[9];
    const float* bdt   = (const float*)d_in[10];
    const float* A_log = (const float*)d_in[11];
    const float* Wout  = (const float*)d_in[12];
    const float* bout  = (const float*)d_in[13];
    float* out = (float*)d_out;

    const int Bb = 2, L = 2048, D = 1024, N = 16;
    const int M = Bb * L;            // 4096
    const size_t MD = (size_t)M * D; // 4M

    float* ws   = (float*)d_ws;
    float* xsb  = ws;                         // [M][D]
    float* dtb  = xsb + MD;                   // [M][D]
    float* BCb  = dtb + MD;                   // [M][32]
    float* Pb   = BCb + (size_t)M * 32;       // [B][D][CHUNKS][16]
    float* Hlb  = Pb  + (size_t)Bb * D * CHUNKS * 16;
    unsigned short* xbf   = (unsigned short*)(Hlb + (size_t)Bb * D * CHUNKS * 16);
    unsigned short* Wzt   = xbf + MD;          // xbf reused as ybf after projections
    unsigned short* Wxt   = Wzt + (size_t)D * D;
    unsigned short* Wdtt  = Wxt + (size_t)D * D;
    unsigned short* Woutt = Wdtt + (size_t)D * D;
    float* zb = out;   // z staged in d_out [M][D]; fully overwritten by final GEMM

    dim3 blk(256);
    dim3 gridT(D / 64, D / 64, 4);
    dim3 gridG(D / GBN, M / GBM);           // (16, 32) all big GEMMs

    convert_bf16<<<dim3((unsigned)(MD / 4 / 256)), blk, 0, stream>>>(x, xbf, (int)(MD / 4));
    transpose4_bf16<<<gridT, blk, 0, stream>>>(Wz, Wx, Wdt, Wout,
                                               Wzt, Wxt, Wdtt, Woutt, D);

    // projections: out[m][d], bias per col
    gemm_bt<<<gridG, blk, 0, stream>>>(xbf, Wzt,  bz,  zb,  D, D, 1);
    gemm_bt<<<gridG, blk, 0, stream>>>(xbf, Wxt,  bx,  xsb, D, D, 0);
    gemm_bt<<<gridG, blk, 0, stream>>>(xbf, Wdtt, bdt, dtb, D, D, 2);
    bc_proj<<<dim3(M / 8), blk, 0, stream>>>(x, WB, bB, WC, bC, BCb, D, M);

    // chunked scan
    dim3 gridScan(D / 256, CHUNKS, Bb);     // (4, 64, 2)
    scan_phase1<<<gridScan, blk, 0, stream>>>(xsb, dtb, BCb, A_log, Pb, Hlb, L, D, M);
    scan_phase2<<<dim3(Bb * D * N / 256), blk, 0, stream>>>(Pb, Hlb, D, N);
    scan_phase3<<<gridScan, blk, 0, stream>>>(xsb, dtb, BCb, zb, A_log, Hlb,
                                              xbf /* ybf */, L, D, M);

    // output projection
    gemm_bt<<<gridG, blk, 0, stream>>>(xbf, Woutt, bout, out, D, D, 0);
}

// Round 12
// 179.064 us; speedup vs baseline: 1.7144x; 1.1171x over previous
//
#include <hip/hip_runtime.h>
#include <math.h>

#define CHUNKS 64
#define LCH    32    // L / CHUNKS

// m97-style MFMA GEMM tile
#define GBM 128
#define GBN 64
#define GBK 32

typedef __attribute__((ext_vector_type(8))) short bf16x8;
typedef __attribute__((ext_vector_type(4))) float f32x4;
typedef __attribute__((ext_vector_type(8))) unsigned short us8;
typedef __attribute__((ext_vector_type(4))) unsigned short us4;

typedef __attribute__((address_space(1))) const unsigned int gu32;
typedef __attribute__((address_space(3))) unsigned int lu32;

__device__ __forceinline__ void gload16(const unsigned short* g, unsigned short* l) {
    // async global->LDS, 16B per lane; LDS dest = uniform base + lane*16
    __builtin_amdgcn_global_load_lds((gu32*)g, (lu32*)l, 16, 0, 0);
}

__device__ __forceinline__ unsigned short f2bf(float f) {
    unsigned int u = __float_as_uint(f);
    unsigned int r = (u + 0x7FFFu + ((u >> 16) & 1u)) >> 16;   // RNE
    return (unsigned short)r;
}

// ---------------- conversions ----------------
__global__ __launch_bounds__(256) void convert_bf16(
    const float* __restrict__ in, unsigned short* __restrict__ out, int n4)
{
    int i = blockIdx.x * 256 + threadIdx.x;
    if (i < n4) {
        float4 v = ((const float4*)in)[i];
        us4 u;
        u[0] = f2bf(v.x); u[1] = f2bf(v.y); u[2] = f2bf(v.z); u[3] = f2bf(v.w);
        ((us4*)out)[i] = u;
    }
}

// 4 weight transposes in one dispatch: W[k][n] f32 -> Wt[n][k] bf16
__global__ __launch_bounds__(256) void transpose4_bf16(
    const float* __restrict__ W0, const float* __restrict__ W1,
    const float* __restrict__ W2, const float* __restrict__ W3,
    unsigned short* __restrict__ T0, unsigned short* __restrict__ T1,
    unsigned short* __restrict__ T2, unsigned short* __restrict__ T3, int D)
{
    const float* W = (blockIdx.z == 0) ? W0 : (blockIdx.z == 1) ? W1
                   : (blockIdx.z == 2) ? W2 : W3;
    unsigned short* Wt = (blockIdx.z == 0) ? T0 : (blockIdx.z == 1) ? T1
                       : (blockIdx.z == 2) ? T2 : T3;

    __shared__ float Ls[64][65];
    const int n0 = blockIdx.x * 64;
    const int k0 = blockIdx.y * 64;
    const int tx = threadIdx.x;

#pragma unroll
    for (int i = 0; i < 4; i++) {
        int idx = tx + i * 256;
        int kr = idx >> 4;
        int ng = idx & 15;
        float4 v = *(const float4*)&W[(size_t)(k0 + kr) * D + n0 + ng * 4];
        Ls[kr][ng * 4 + 0] = v.x;
        Ls[kr][ng * 4 + 1] = v.y;
        Ls[kr][ng * 4 + 2] = v.z;
        Ls[kr][ng * 4 + 3] = v.w;
    }
    __syncthreads();
#pragma unroll
    for (int i = 0; i < 4; i++) {
        int idx = tx + i * 256;
        int nr = idx >> 4;
        int kg = idx & 15;
        us4 u;
#pragma unroll
        for (int j = 0; j < 4; j++) u[j] = f2bf(Ls[kg * 4 + j][nr]);
        *(us4*)&Wt[(size_t)(n0 + nr) * D + k0 + kg * 4] = u;
    }
}

// ---------------- shared MFMA GEMM core with bank-conflict swizzle ----------
// Staging: lane l fetches global 16B chunk q = (l&3)^((l>>3)&3) of row l>>2
// (per 16-row chunk); linear LDS dest. Read: slot = lk ^ ((row>>1)&3).
// Over 16 consecutive rows this covers all 8 phys 16B slots twice = minimal
// aliasing (2-way, free per m136).
__device__ __forceinline__ void gemm_core(
    const unsigned short* __restrict__ A, const unsigned short* __restrict__ B,
    unsigned short* As, unsigned short* Bs,
    int brow, int bcol, int K, f32x4 acc[4][2],
    int wave, int lane, int wr, int wc, int lrow, int lk)
{
    const int srow = lane >> 2;
    const int sq   = ((lane & 3) ^ ((lane >> 3) & 3)) * 8;   // swizzled source chunk

#pragma unroll
    for (int m = 0; m < 4; m++)
#pragma unroll
        for (int n = 0; n < 2; n++) acc[m][n] = (f32x4)(0.f);

    for (int k0 = 0; k0 < K; k0 += GBK) {
        gload16(&A[(size_t)(brow + wave * 32      + srow) * K + k0 + sq],
                &As[(wave * 32) * GBK]);
        gload16(&A[(size_t)(brow + wave * 32 + 16 + srow) * K + k0 + sq],
                &As[(wave * 32 + 16) * GBK]);
        gload16(&B[(size_t)(bcol + wave * 16      + srow) * K + k0 + sq],
                &Bs[(wave * 16) * GBK]);
        __syncthreads();

        bf16x8 av[4], bv[2];
#pragma unroll
        for (int m = 0; m < 4; m++) {
            int row = wr * 64 + m * 16 + lrow;
            av[m] = *(const bf16x8*)&As[row * GBK + ((lk ^ ((row >> 1) & 3)) * 8)];
        }
#pragma unroll
        for (int n = 0; n < 2; n++) {
            int row = wc * 32 + n * 16 + lrow;
            bv[n] = *(const bf16x8*)&Bs[row * GBK + ((lk ^ ((row >> 1) & 3)) * 8)];
        }
#pragma unroll
        for (int m = 0; m < 4; m++)
#pragma unroll
            for (int n = 0; n < 2; n++)
                acc[m][n] = __builtin_amdgcn_mfma_f32_16x16x32_bf16(
                    av[m], bv[n], acc[m][n], 0, 0, 0);
        __syncthreads();
    }
}

// Fused triple projection: one dispatch, widx = blockIdx.x>>4 selects weight,
// bias, activation (0: sigmoid, 1: none, 2: softplus) and output buffer.
__global__ __launch_bounds__(256) void proj3_gemm(
    const unsigned short* __restrict__ A,
    const unsigned short* __restrict__ W0, const unsigned short* __restrict__ W1,
    const unsigned short* __restrict__ W2,
    const float* __restrict__ b0, const float* __restrict__ b1,
    const float* __restrict__ b2,
    float* __restrict__ o0, float* __restrict__ o1, float* __restrict__ o2,
    int K, int Nc)
{
    __shared__ unsigned short As[GBM * GBK];
    __shared__ unsigned short Bs[GBN * GBK];

    const int widx = blockIdx.x >> 4;
    const unsigned short* B = (widx == 0) ? W0 : (widx == 1) ? W1 : W2;
    const float* bias = (widx == 0) ? b0 : (widx == 1) ? b1 : b2;
    float* out = (widx == 0) ? o0 : (widx == 1) ? o1 : o2;

    const int tx = threadIdx.x;
    const int wave = tx >> 6;
    const int lane = tx & 63;
    const int wr = wave >> 1, wc = wave & 1;
    const int lrow = lane & 15, lk = lane >> 4;
    const int brow = blockIdx.y * GBM;
    const int bcol = (blockIdx.x & 15) * GBN;

    f32x4 acc[4][2];
    gemm_core(A, B, As, Bs, brow, bcol, K, acc, wave, lane, wr, wc, lrow, lk);

#pragma unroll
    for (int n = 0; n < 2; n++) {
        int col = bcol + wc * 32 + n * 16 + lrow;
        float bval = bias[col];
#pragma unroll
        for (int m = 0; m < 4; m++) {
#pragma unroll
            for (int r = 0; r < 4; r++) {
                int row = brow + wr * 64 + m * 16 + lk * 4 + r;
                float v = acc[m][n][r] + bval;
                if (widx == 0) v = 1.f / (1.f + __expf(-v));
                else if (widx == 2) v = (v > 20.f) ? v : log1pf(__expf(v));
                out[(size_t)row * Nc + col] = v;
            }
        }
    }
}

// Final GEMM (no activation)
__global__ __launch_bounds__(256) void gemm_bt(
    const unsigned short* __restrict__ A, const unsigned short* __restrict__ B,
    const float* __restrict__ bias, float* __restrict__ out, int K, int ldo)
{
    __shared__ unsigned short As[GBM * GBK];
    __shared__ unsigned short Bs[GBN * GBK];

    const int tx = threadIdx.x;
    const int wave = tx >> 6;
    const int lane = tx & 63;
    const int wr = wave >> 1, wc = wave & 1;
    const int lrow = lane & 15, lk = lane >> 4;
    const int brow = blockIdx.y * GBM;
    const int bcol = blockIdx.x * GBN;

    f32x4 acc[4][2];
    gemm_core(A, B, As, Bs, brow, bcol, K, acc, wave, lane, wr, wc, lrow, lk);

#pragma unroll
    for (int n = 0; n < 2; n++) {
        int col = bcol + wc * 32 + n * 16 + lrow;
        float bval = bias[col];
#pragma unroll
        for (int m = 0; m < 4; m++) {
#pragma unroll
            for (int r = 0; r < 4; r++) {
                int row = brow + wr * 64 + m * 16 + lk * 4 + r;
                out[(size_t)row * ldo + col] = acc[m][n][r] + bval;
            }
        }
    }
}

// ---------------- fused B+C projection ----------------
// BC[m][32]: cols 0..15 = Bm, 16..31 = C.
__global__ __launch_bounds__(256) void bc_proj(
    const float* __restrict__ x,
    const float* __restrict__ WB, const float* __restrict__ bB,
    const float* __restrict__ WC, const float* __restrict__ bC,
    float* __restrict__ BC, int K, int M)
{
    __shared__ unsigned short Wl[32 * 1024];   // 64 KB

    const int tx = threadIdx.x;

#pragma unroll
    for (int i = 0; i < 16; i++) {
        int e = tx + i * 256;
        int k = e >> 2;
        int n0 = (e & 3) * 4;
        float4 v = ((const float4*)WB)[e];
        float vv[4] = {v.x, v.y, v.z, v.w};
#pragma unroll
        for (int j = 0; j < 4; j++) {
            int n = n0 + j;
            Wl[n * 1024 + (((k & ~7) ^ ((n & 15) << 3)) | (k & 7))] = f2bf(vv[j]);
        }
    }
#pragma unroll
    for (int i = 0; i < 16; i++) {
        int e = tx + i * 256;
        int k = e >> 2;
        int n0 = (e & 3) * 4;
        float4 v = ((const float4*)WC)[e];
        float vv[4] = {v.x, v.y, v.z, v.w};
#pragma unroll
        for (int j = 0; j < 4; j++) {
            int n = 16 + n0 + j;
            Wl[n * 1024 + (((k & ~7) ^ ((n & 15) << 3)) | (k & 7))] = f2bf(vv[j]);
        }
    }
    __syncthreads();

    const int n = tx & 31;
    const int r = tx >> 5;
    const int row = blockIdx.x * 8 + r;

    const unsigned short* wrow = &Wl[n * 1024];
    const int sw = (n & 15) << 3;
    const float* xrow = &x[(size_t)row * K];

    float acc = 0.f;
    for (int kb = 0; kb < K; kb += 8) {
        us8 w8 = *(const us8*)&wrow[kb ^ sw];
        float4 xa = *(const float4*)&xrow[kb];
        float4 xb = *(const float4*)&xrow[kb + 4];
        float xv[8] = {xa.x, xa.y, xa.z, xa.w, xb.x, xb.y, xb.z, xb.w};
#pragma unroll
        for (int j = 0; j < 8; j++) {
            acc = fmaf(xv[j], __uint_as_float((unsigned)(unsigned short)w8[j] << 16), acc);
        }
    }

    float bias = (n < 16) ? bB[n] : bC[n - 16];
    BC[(size_t)row * 32 + n] = acc + bias;
}

// ---------------- chunked scan: thread = one d, all 16 states in regs ------
__global__ __launch_bounds__(256) void scan_phase1(
    const float* __restrict__ xs, const float* __restrict__ dt,
    const float* __restrict__ BC, const float* __restrict__ A_log,
    float* __restrict__ P, float* __restrict__ Hl, int L, int D, int M)
{
    const int tx = threadIdx.x;
    const int d  = blockIdx.x * 256 + tx;
    const int c  = blockIdx.y;
    const int b  = blockIdx.z;
    const int m0 = b * L + c * LCH;

    __shared__ float bcs[LCH][32];
    {
        int row = tx >> 3, col = (tx & 7) * 4;
        *(f32x4*)&bcs[row][col] = *(const f32x4*)&BC[(size_t)(m0 + row) * 32 + col];
    }
    __syncthreads();

    float Av[16];
#pragma unroll
    for (int i = 0; i < 4; i++) {
        f32x4 a4 = *(const f32x4*)&A_log[d * 16 + i * 4];
#pragma unroll
        for (int j = 0; j < 4; j++) Av[i * 4 + j] = -__expf(a4[j]);
    }

    float h[16];
#pragma unroll
    for (int n = 0; n < 16; n++) h[n] = 0.f;
    float dts = 0.f;

    const size_t base = (size_t)m0 * D + d;
    float dtv = dt[base], xv = xs[base];
    for (int t = 0; t < LCH; t++) {
        float dtn = 0.f, xvn = 0.f;
        if (t + 1 < LCH) {
            dtn = dt[base + (size_t)(t + 1) * D];
            xvn = xs[base + (size_t)(t + 1) * D];
        }
        float xdt = xv * dtv;
        dts += dtv;
        f32x4 bm[4];
#pragma unroll
        for (int i = 0; i < 4; i++) bm[i] = *(const f32x4*)&bcs[t][i * 4];
#pragma unroll
        for (int n = 0; n < 16; n++) {
            float a = __expf(dtv * Av[n]);
            h[n] = fmaf(a, h[n], xdt * bm[n >> 2][n & 3]);
        }
        dtv = dtn; xv = xvn;
    }

    size_t idx = (((size_t)b * D + d) * CHUNKS + c) * 16;
#pragma unroll
    for (int i = 0; i < 4; i++) {
        f32x4 p4, h4;
#pragma unroll
        for (int j = 0; j < 4; j++) {
            p4[j] = __expf(Av[i * 4 + j] * dts);
            h4[j] = h[i * 4 + j];
        }
        *(f32x4*)&P[idx + i * 4]  = p4;
        *(f32x4*)&Hl[idx + i * 4] = h4;
    }
}

__global__ __launch_bounds__(256) void scan_phase2(
    const float* __restrict__ P, float* __restrict__ Hl, int D, int N)
{
    const int tid = blockIdx.x * 256 + threadIdx.x;   // B*D*N
    const int n = tid & 15;
    const int dd = (tid >> 4) & 1023;
    const int b = tid >> 14;

    size_t base = (((size_t)b * D + dd) * CHUNKS) * 16 + n;
    float run = 0.f;
#pragma unroll 4
    for (int c = 0; c < CHUNKS; c++) {
        float p   = P[base + (size_t)c * 16];
        float tmp = Hl[base + (size_t)c * 16];
        Hl[base + (size_t)c * 16] = run;
        run = fmaf(p, run, tmp);
    }
}

__global__ __launch_bounds__(256) void scan_phase3(
    const float* __restrict__ xs, const float* __restrict__ dt,
    const float* __restrict__ BC, const float* __restrict__ z,
    const float* __restrict__ A_log, const float* __restrict__ Hin,
    unsigned short* __restrict__ ybf, int L, int D, int M)
{
    const int tx = threadIdx.x;
    const int d  = blockIdx.x * 256 + tx;
    const int c  = blockIdx.y;
    const int b  = blockIdx.z;
    const int m0 = b * L + c * LCH;

    __shared__ float bcs[LCH][32];
    {
        int row = tx >> 3, col = (tx & 7) * 4;
        *(f32x4*)&bcs[row][col] = *(const f32x4*)&BC[(size_t)(m0 + row) * 32 + col];
    }
    __syncthreads();

    float Av[16];
#pragma unroll
    for (int i = 0; i < 4; i++) {
        f32x4 a4 = *(const f32x4*)&A_log[d * 16 + i * 4];
#pragma unroll
        for (int j = 0; j < 4; j++) Av[i * 4 + j] = -__expf(a4[j]);
    }

    float h[16];
    {
        size_t hidx = (((size_t)b * D + d) * CHUNKS + c) * 16;
#pragma unroll
        for (int i = 0; i < 4; i++) {
            f32x4 h4 = *(const f32x4*)&Hin[hidx + i * 4];
#pragma unroll
            for (int j = 0; j < 4; j++) h[i * 4 + j] = h4[j];
        }
    }

    const size_t base = (size_t)m0 * D + d;
    float dtv = dt[base], xv = xs[base], zv = z[base];
    for (int t = 0; t < LCH; t++) {
        float dtn = 0.f, xvn = 0.f, zvn = 0.f;
        if (t + 1 < LCH) {
            dtn = dt[base + (size_t)(t + 1) * D];
            xvn = xs[base + (size_t)(t + 1) * D];
            zvn = z[base + (size_t)(t + 1) * D];
        }
        float xdt = xv * dtv;
        f32x4 bm[4], cm[4];
#pragma unroll
        for (int i = 0; i < 4; i++) {
            bm[i] = *(const f32x4*)&bcs[t][i * 4];
            cm[i] = *(const f32x4*)&bcs[t][16 + i * 4];
        }
        float y = 0.f;
#pragma unroll
        for (int n = 0; n < 16; n++) {
            float a = __expf(dtv * Av[n]);
            h[n] = fmaf(a, h[n], xdt * bm[n >> 2][n & 3]);
            y = fmaf(h[n], cm[n >> 2][n & 3], y);
        }
        ybf[base + (size_t)t * D] = f2bf(y * zv);
        dtv = dtn; xv = xvn; zv = zvn;
    }
}

extern "C" void kernel_launch(void* const* d_in, const int* in_sizes, int n_in,
                              void* d_out, int out_size, void* d_ws, size_t ws_size,
                              hipStream_t stream) {
    const float* x     = (const float*)d_in[0];
    const float* Wz    = (const float*)d_in[1];
    const float* bz    = (const float*)d_in[2];
    const float* Wx    = (const float*)d_in[3];
    const float* bx    = (const float*)d_in[4];
    const float* WB    = (const float*)d_in[5];
    const float* bB    = (const float*)d_in[6];
    const float* WC    = (const float*)d_in[7];
    const float* bC    = (const float*)d_in[8];
    const float* Wdt   = (const float*)d_in[9];
    const float* bdt   = (const float*)d_in[10];
    const float* A_log = (const float*)d_in[11];
    const float* Wout  = (const float*)d_in[12];
    const float* bout  = (const float*)d_in[13];
    float* out = (float*)d_out;

    const int Bb = 2, L = 2048, D = 1024, N = 16;
    const int M = Bb * L;            // 4096
    const size_t MD = (size_t)M * D; // 4M

    float* ws   = (float*)d_ws;
    float* xsb  = ws;                         // [M][D]
    float* dtb  = xsb + MD;                   // [M][D]
    float* BCb  = dtb + MD;                   // [M][32]
    float* Pb   = BCb + (size_t)M * 32;       // [B][D][CHUNKS][16]
    float* Hlb  = Pb  + (size_t)Bb * D * CHUNKS * 16;
    unsigned short* xbf   = (unsigned short*)(Hlb + (size_t)Bb * D * CHUNKS * 16);
    unsigned short* Wzt   = xbf + MD;          // xbf reused as ybf after projections
    unsigned short* Wxt   = Wzt + (size_t)D * D;
    unsigned short* Wdtt  = Wxt + (size_t)D * D;
    unsigned short* Woutt = Wdtt + (size_t)D * D;
    float* zb = out;   // z staged in d_out [M][D]; fully overwritten by final GEMM

    dim3 blk(256);
    dim3 gridT(D / 64, D / 64, 4);

    convert_bf16<<<dim3((unsigned)(MD / 4 / 256)), blk, 0, stream>>>(x, xbf, (int)(MD / 4));
    transpose4_bf16<<<gridT, blk, 0, stream>>>(Wz, Wx, Wdt, Wout,
                                               Wzt, Wxt, Wdtt, Woutt, D);

    // fused triple projection: grid (48, 32) = 1536 blocks
    proj3_gemm<<<dim3(3 * D / GBN, M / GBM), blk, 0, stream>>>(
        xbf, Wzt, Wxt, Wdtt, bz, bx, bdt, zb, xsb, dtb, D, D);
    bc_proj<<<dim3(M / 8), blk, 0, stream>>>(x, WB, bB, WC, bC, BCb, D, M);

    // chunked scan
    dim3 gridScan(D / 256, CHUNKS, Bb);     // (4, 64, 2)
    scan_phase1<<<gridScan, blk, 0, stream>>>(xsb, dtb, BCb, A_log, Pb, Hlb, L, D, M);
    scan_phase2<<<dim3(Bb * D * N / 256), blk, 0, stream>>>(Pb, Hlb, D, N);
    scan_phase3<<<gridScan, blk, 0, stream>>>(xsb, dtb, BCb, zb, A_log, Hlb,
                                              xbf /* ybf */, L, D, M);

    // output projection
    gemm_bt<<<dim3(D / GBN, M / GBM), blk, 0, stream>>>(xbf, Woutt, bout, out, D, D);
}

// Round 13
// 173.404 us; speedup vs baseline: 1.7704x; 1.0326x over previous
//
#include <hip/hip_runtime.h>
#include <math.h>

#define CHUNKS 64
#define LCH    32    // L / CHUNKS

// m97 MFMA GEMM tile: 128x128x32, 4 waves (2x2), 64x64 per wave
#define GBM 128
#define GBN 128
#define GBK 32

typedef __attribute__((ext_vector_type(8))) short bf16x8;
typedef __attribute__((ext_vector_type(4))) float f32x4;
typedef __attribute__((ext_vector_type(8))) unsigned short us8;
typedef __attribute__((ext_vector_type(4))) unsigned short us4;

typedef __attribute__((address_space(1))) const unsigned int gu32;
typedef __attribute__((address_space(3))) unsigned int lu32;

__device__ __forceinline__ void gload16(const unsigned short* g, unsigned short* l) {
    // async global->LDS, 16B per lane; LDS dest = uniform base + lane*16
    __builtin_amdgcn_global_load_lds((gu32*)g, (lu32*)l, 16, 0, 0);
}

__device__ __forceinline__ unsigned short f2bf(float f) {
    unsigned int u = __float_as_uint(f);
    unsigned int r = (u + 0x7FFFu + ((u >> 16) & 1u)) >> 16;   // RNE
    return (unsigned short)r;
}

// ---------------- conversions ----------------
__global__ __launch_bounds__(256) void convert_bf16(
    const float* __restrict__ in, unsigned short* __restrict__ out, int n4)
{
    int i = blockIdx.x * 256 + threadIdx.x;
    if (i < n4) {
        float4 v = ((const float4*)in)[i];
        us4 u;
        u[0] = f2bf(v.x); u[1] = f2bf(v.y); u[2] = f2bf(v.z); u[3] = f2bf(v.w);
        ((us4*)out)[i] = u;
    }
}

// 4 weight transposes in one dispatch: W[k][n] f32 -> Wt[n][k] bf16
__global__ __launch_bounds__(256) void transpose4_bf16(
    const float* __restrict__ W0, const float* __restrict__ W1,
    const float* __restrict__ W2, const float* __restrict__ W3,
    unsigned short* __restrict__ T0, unsigned short* __restrict__ T1,
    unsigned short* __restrict__ T2, unsigned short* __restrict__ T3, int D)
{
    const float* W = (blockIdx.z == 0) ? W0 : (blockIdx.z == 1) ? W1
                   : (blockIdx.z == 2) ? W2 : W3;
    unsigned short* Wt = (blockIdx.z == 0) ? T0 : (blockIdx.z == 1) ? T1
                       : (blockIdx.z == 2) ? T2 : T3;

    __shared__ float Ls[64][65];
    const int n0 = blockIdx.x * 64;
    const int k0 = blockIdx.y * 64;
    const int tx = threadIdx.x;

#pragma unroll
    for (int i = 0; i < 4; i++) {
        int idx = tx + i * 256;
        int kr = idx >> 4;
        int ng = idx & 15;
        float4 v = *(const float4*)&W[(size_t)(k0 + kr) * D + n0 + ng * 4];
        Ls[kr][ng * 4 + 0] = v.x;
        Ls[kr][ng * 4 + 1] = v.y;
        Ls[kr][ng * 4 + 2] = v.z;
        Ls[kr][ng * 4 + 3] = v.w;
    }
    __syncthreads();
#pragma unroll
    for (int i = 0; i < 4; i++) {
        int idx = tx + i * 256;
        int nr = idx >> 4;
        int kg = idx & 15;
        us4 u;
#pragma unroll
        for (int j = 0; j < 4; j++) u[j] = f2bf(Ls[kg * 4 + j][nr]);
        *(us4*)&Wt[(size_t)(n0 + nr) * D + k0 + kg * 4] = u;
    }
}

// ---------------- m97 128x128 MFMA GEMM core, swizzled staging ----------
// Staging: lane l fetches global 16B chunk q=(l&3)^((l>>3)&3) of its row;
// linear LDS dest. Read slot = lk ^ ((row>>1)&3). Bank-conflict-free
// (verified round 12: SQ_LDS_BANK_CONFLICT 1.57M -> 0).
// Per K-step per wave: 16 MFMA + 8 ds_read_b128 + 4 gload16.
__device__ __forceinline__ void gemm_core(
    const unsigned short* __restrict__ A, const unsigned short* __restrict__ B,
    unsigned short* As, unsigned short* Bs,
    int brow, int bcol, int K, f32x4 acc[4][4],
    int wave, int lane, int wr, int wc, int lrow, int lk)
{
    const int srow = lane >> 2;
    const int sq   = ((lane & 3) ^ ((lane >> 3) & 3)) * 8;   // swizzled source chunk

#pragma unroll
    for (int m = 0; m < 4; m++)
#pragma unroll
        for (int n = 0; n < 4; n++) acc[m][n] = (f32x4)(0.f);

    for (int k0 = 0; k0 < K; k0 += GBK) {
        // wave w stages A rows [w*32, w*32+32) and B rows [w*32, w*32+32)
        gload16(&A[(size_t)(brow + wave * 32      + srow) * K + k0 + sq],
                &As[(wave * 32) * GBK]);
        gload16(&A[(size_t)(brow + wave * 32 + 16 + srow) * K + k0 + sq],
                &As[(wave * 32 + 16) * GBK]);
        gload16(&B[(size_t)(bcol + wave * 32      + srow) * K + k0 + sq],
                &Bs[(wave * 32) * GBK]);
        gload16(&B[(size_t)(bcol + wave * 32 + 16 + srow) * K + k0 + sq],
                &Bs[(wave * 32 + 16) * GBK]);
        __syncthreads();

        bf16x8 av[4], bv[4];
#pragma unroll
        for (int m = 0; m < 4; m++) {
            int row = wr * 64 + m * 16 + lrow;
            av[m] = *(const bf16x8*)&As[row * GBK + ((lk ^ ((row >> 1) & 3)) * 8)];
        }
#pragma unroll
        for (int n = 0; n < 4; n++) {
            int row = wc * 64 + n * 16 + lrow;
            bv[n] = *(const bf16x8*)&Bs[row * GBK + ((lk ^ ((row >> 1) & 3)) * 8)];
        }
#pragma unroll
        for (int m = 0; m < 4; m++)
#pragma unroll
            for (int n = 0; n < 4; n++)
                acc[m][n] = __builtin_amdgcn_mfma_f32_16x16x32_bf16(
                    av[m], bv[n], acc[m][n], 0, 0, 0);
        __syncthreads();
    }
}

// Fused triple projection: widx = blockIdx.x>>3 selects weight/bias/act/output.
__global__ __launch_bounds__(256) void proj3_gemm(
    const unsigned short* __restrict__ A,
    const unsigned short* __restrict__ W0, const unsigned short* __restrict__ W1,
    const unsigned short* __restrict__ W2,
    const float* __restrict__ b0, const float* __restrict__ b1,
    const float* __restrict__ b2,
    float* __restrict__ o0, float* __restrict__ o1, float* __restrict__ o2,
    int K, int Nc)
{
    __shared__ unsigned short As[GBM * GBK];   // 8 KB
    __shared__ unsigned short Bs[GBN * GBK];   // 8 KB

    const int widx = blockIdx.x >> 3;
    const unsigned short* B = (widx == 0) ? W0 : (widx == 1) ? W1 : W2;
    const float* bias = (widx == 0) ? b0 : (widx == 1) ? b1 : b2;
    float* out = (widx == 0) ? o0 : (widx == 1) ? o1 : o2;

    const int tx = threadIdx.x;
    const int wave = tx >> 6;
    const int lane = tx & 63;
    const int wr = wave >> 1, wc = wave & 1;
    const int lrow = lane & 15, lk = lane >> 4;
    const int brow = blockIdx.y * GBM;
    const int bcol = (blockIdx.x & 7) * GBN;

    f32x4 acc[4][4];
    gemm_core(A, B, As, Bs, brow, bcol, K, acc, wave, lane, wr, wc, lrow, lk);

#pragma unroll
    for (int n = 0; n < 4; n++) {
        int col = bcol + wc * 64 + n * 16 + lrow;
        float bval = bias[col];
#pragma unroll
        for (int m = 0; m < 4; m++) {
#pragma unroll
            for (int r = 0; r < 4; r++) {
                int row = brow + wr * 64 + m * 16 + lk * 4 + r;
                float v = acc[m][n][r] + bval;
                if (widx == 0) v = 1.f / (1.f + __expf(-v));
                else if (widx == 2) v = (v > 20.f) ? v : log1pf(__expf(v));
                out[(size_t)row * Nc + col] = v;
            }
        }
    }
}

// Final GEMM (no activation)
__global__ __launch_bounds__(256) void gemm_bt(
    const unsigned short* __restrict__ A, const unsigned short* __restrict__ B,
    const float* __restrict__ bias, float* __restrict__ out, int K, int ldo)
{
    __shared__ unsigned short As[GBM * GBK];
    __shared__ unsigned short Bs[GBN * GBK];

    const int tx = threadIdx.x;
    const int wave = tx >> 6;
    const int lane = tx & 63;
    const int wr = wave >> 1, wc = wave & 1;
    const int lrow = lane & 15, lk = lane >> 4;
    const int brow = blockIdx.y * GBM;
    const int bcol = blockIdx.x * GBN;

    f32x4 acc[4][4];
    gemm_core(A, B, As, Bs, brow, bcol, K, acc, wave, lane, wr, wc, lrow, lk);

#pragma unroll
    for (int n = 0; n < 4; n++) {
        int col = bcol + wc * 64 + n * 16 + lrow;
        float bval = bias[col];
#pragma unroll
        for (int m = 0; m < 4; m++) {
#pragma unroll
            for (int r = 0; r < 4; r++) {
                int row = brow + wr * 64 + m * 16 + lk * 4 + r;
                out[(size_t)row * ldo + col] = acc[m][n][r] + bval;
            }
        }
    }
}

// ---------------- fused B+C projection ----------------
// BC[m][32]: cols 0..15 = Bm, 16..31 = C.
__global__ __launch_bounds__(256) void bc_proj(
    const float* __restrict__ x,
    const float* __restrict__ WB, const float* __restrict__ bB,
    const float* __restrict__ WC, const float* __restrict__ bC,
    float* __restrict__ BC, int K, int M)
{
    __shared__ unsigned short Wl[32 * 1024];   // 64 KB

    const int tx = threadIdx.x;

#pragma unroll
    for (int i = 0; i < 16; i++) {
        int e = tx + i * 256;
        int k = e >> 2;
        int n0 = (e & 3) * 4;
        float4 v = ((const float4*)WB)[e];
        float vv[4] = {v.x, v.y, v.z, v.w};
#pragma unroll
        for (int j = 0; j < 4; j++) {
            int n = n0 + j;
            Wl[n * 1024 + (((k & ~7) ^ ((n & 15) << 3)) | (k & 7))] = f2bf(vv[j]);
        }
    }
#pragma unroll
    for (int i = 0; i < 16; i++) {
        int e = tx + i * 256;
        int k = e >> 2;
        int n0 = (e & 3) * 4;
        float4 v = ((const float4*)WC)[e];
        float vv[4] = {v.x, v.y, v.z, v.w};
#pragma unroll
        for (int j = 0; j < 4; j++) {
            int n = 16 + n0 + j;
            Wl[n * 1024 + (((k & ~7) ^ ((n & 15) << 3)) | (k & 7))] = f2bf(vv[j]);
        }
    }
    __syncthreads();

    const int n = tx & 31;
    const int r = tx >> 5;
    const int row = blockIdx.x * 8 + r;

    const unsigned short* wrow = &Wl[n * 1024];
    const int sw = (n & 15) << 3;
    const float* xrow = &x[(size_t)row * K];

    float acc = 0.f;
    for (int kb = 0; kb < K; kb += 8) {
        us8 w8 = *(const us8*)&wrow[kb ^ sw];
        float4 xa = *(const float4*)&xrow[kb];
        float4 xb = *(const float4*)&xrow[kb + 4];
        float xv[8] = {xa.x, xa.y, xa.z, xa.w, xb.x, xb.y, xb.z, xb.w};
#pragma unroll
        for (int j = 0; j < 8; j++) {
            acc = fmaf(xv[j], __uint_as_float((unsigned)(unsigned short)w8[j] << 16), acc);
        }
    }

    float bias = (n < 16) ? bB[n] : bC[n - 16];
    BC[(size_t)row * 32 + n] = acc + bias;
}

// ---------------- chunked scan: thread = one d, all 16 states in regs ------
__global__ __launch_bounds__(256) void scan_phase1(
    const float* __restrict__ xs, const float* __restrict__ dt,
    const float* __restrict__ BC, const float* __restrict__ A_log,
    float* __restrict__ P, float* __restrict__ Hl, int L, int D, int M)
{
    const int tx = threadIdx.x;
    const int d  = blockIdx.x * 256 + tx;
    const int c  = blockIdx.y;
    const int b  = blockIdx.z;
    const int m0 = b * L + c * LCH;

    __shared__ float bcs[LCH][32];
    {
        int row = tx >> 3, col = (tx & 7) * 4;
        *(f32x4*)&bcs[row][col] = *(const f32x4*)&BC[(size_t)(m0 + row) * 32 + col];
    }
    __syncthreads();

    float Av[16];
#pragma unroll
    for (int i = 0; i < 4; i++) {
        f32x4 a4 = *(const f32x4*)&A_log[d * 16 + i * 4];
#pragma unroll
        for (int j = 0; j < 4; j++) Av[i * 4 + j] = -__expf(a4[j]);
    }

    float h[16];
#pragma unroll
    for (int n = 0; n < 16; n++) h[n] = 0.f;
    float dts = 0.f;

    const size_t base = (size_t)m0 * D + d;
    float dtv = dt[base], xv = xs[base];
    for (int t = 0; t < LCH; t++) {
        float dtn = 0.f, xvn = 0.f;
        if (t + 1 < LCH) {
            dtn = dt[base + (size_t)(t + 1) * D];
            xvn = xs[base + (size_t)(t + 1) * D];
        }
        float xdt = xv * dtv;
        dts += dtv;
        f32x4 bm[4];
#pragma unroll
        for (int i = 0; i < 4; i++) bm[i] = *(const f32x4*)&bcs[t][i * 4];
#pragma unroll
        for (int n = 0; n < 16; n++) {
            float a = __expf(dtv * Av[n]);
            h[n] = fmaf(a, h[n], xdt * bm[n >> 2][n & 3]);
        }
        dtv = dtn; xv = xvn;
    }

    size_t idx = (((size_t)b * D + d) * CHUNKS + c) * 16;
#pragma unroll
    for (int i = 0; i < 4; i++) {
        f32x4 p4, h4;
#pragma unroll
        for (int j = 0; j < 4; j++) {
            p4[j] = __expf(Av[i * 4 + j] * dts);
            h4[j] = h[i * 4 + j];
        }
        *(f32x4*)&P[idx + i * 4]  = p4;
        *(f32x4*)&Hl[idx + i * 4] = h4;
    }
}

__global__ __launch_bounds__(256) void scan_phase2(
    const float* __restrict__ P, float* __restrict__ Hl, int D, int N)
{
    const int tid = blockIdx.x * 256 + threadIdx.x;   // B*D*N
    const int n = tid & 15;
    const int dd = (tid >> 4) & 1023;
    const int b = tid >> 14;

    size_t base = (((size_t)b * D + dd) * CHUNKS) * 16 + n;
    float run = 0.f;
#pragma unroll 4
    for (int c = 0; c < CHUNKS; c++) {
        float p   = P[base + (size_t)c * 16];
        float tmp = Hl[base + (size_t)c * 16];
        Hl[base + (size_t)c * 16] = run;
        run = fmaf(p, run, tmp);
    }
}

__global__ __launch_bounds__(256) void scan_phase3(
    const float* __restrict__ xs, const float* __restrict__ dt,
    const float* __restrict__ BC, const float* __restrict__ z,
    const float* __restrict__ A_log, const float* __restrict__ Hin,
    unsigned short* __restrict__ ybf, int L, int D, int M)
{
    const int tx = threadIdx.x;
    const int d  = blockIdx.x * 256 + tx;
    const int c  = blockIdx.y;
    const int b  = blockIdx.z;
    const int m0 = b * L + c * LCH;

    __shared__ float bcs[LCH][32];
    {
        int row = tx >> 3, col = (tx & 7) * 4;
        *(f32x4*)&bcs[row][col] = *(const f32x4*)&BC[(size_t)(m0 + row) * 32 + col];
    }
    __syncthreads();

    float Av[16];
#pragma unroll
    for (int i = 0; i < 4; i++) {
        f32x4 a4 = *(const f32x4*)&A_log[d * 16 + i * 4];
#pragma unroll
        for (int j = 0; j < 4; j++) Av[i * 4 + j] = -__expf(a4[j]);
    }

    float h[16];
    {
        size_t hidx = (((size_t)b * D + d) * CHUNKS + c) * 16;
#pragma unroll
        for (int i = 0; i < 4; i++) {
            f32x4 h4 = *(const f32x4*)&Hin[hidx + i * 4];
#pragma unroll
            for (int j = 0; j < 4; j++) h[i * 4 + j] = h4[j];
        }
    }

    const size_t base = (size_t)m0 * D + d;
    float dtv = dt[base], xv = xs[base], zv = z[base];
    for (int t = 0; t < LCH; t++) {
        float dtn = 0.f, xvn = 0.f, zvn = 0.f;
        if (t + 1 < LCH) {
            dtn = dt[base + (size_t)(t + 1) * D];
            xvn = xs[base + (size_t)(t + 1) * D];
            zvn = z[base + (size_t)(t + 1) * D];
        }
        float xdt = xv * dtv;
        f32x4 bm[4], cm[4];
#pragma unroll
        for (int i = 0; i < 4; i++) {
            bm[i] = *(const f32x4*)&bcs[t][i * 4];
            cm[i] = *(const f32x4*)&bcs[t][16 + i * 4];
        }
        float y = 0.f;
#pragma unroll
        for (int n = 0; n < 16; n++) {
            float a = __expf(dtv * Av[n]);
            h[n] = fmaf(a, h[n], xdt * bm[n >> 2][n & 3]);
            y = fmaf(h[n], cm[n >> 2][n & 3], y);
        }
        ybf[base + (size_t)t * D] = f2bf(y * zv);
        dtv = dtn; xv = xvn; zv = zvn;
    }
}

extern "C" void kernel_launch(void* const* d_in, const int* in_sizes, int n_in,
                              void* d_out, int out_size, void* d_ws, size_t ws_size,
                              hipStream_t stream) {
    const float* x     = (const float*)d_in[0];
    const float* Wz    = (const float*)d_in[1];
    const float* bz    = (const float*)d_in[2];
    const float* Wx    = (const float*)d_in[3];
    const float* bx    = (const float*)d_in[4];
    const float* WB    = (const float*)d_in[5];
    const float* bB    = (const float*)d_in[6];
    const float* WC    = (const float*)d_in[7];
    const float* bC    = (const float*)d_in[8];
    const float* Wdt   = (const float*)d_in[9];
    const float* bdt   = (const float*)d_in[10];
    const float* A_log = (const float*)d_in[11];
    const float* Wout  = (const float*)d_in[12];
    const float* bout  = (const float*)d_in[13];
    float* out = (float*)d_out;

    const int Bb = 2, L = 2048, D = 1024, N = 16;
    const int M = Bb * L;            // 4096
    const size_t MD = (size_t)M * D; // 4M

    float* ws   = (float*)d_ws;
    float* xsb  = ws;                         // [M][D]
    float* dtb  = xsb + MD;                   // [M][D]
    float* BCb  = dtb + MD;                   // [M][32]
    float* Pb   = BCb + (size_t)M * 32;       // [B][D][CHUNKS][16]
    float* Hlb  = Pb  + (size_t)Bb * D * CHUNKS * 16;
    unsigned short* xbf   = (unsigned short*)(Hlb + (size_t)Bb * D * CHUNKS * 16);
    unsigned short* Wzt   = xbf + MD;          // xbf reused as ybf after projections
    unsigned short* Wxt   = Wzt + (size_t)D * D;
    unsigned short* Wdtt  = Wxt + (size_t)D * D;
    unsigned short* Woutt = Wdtt + (size_t)D * D;
    float* zb = out;   // z staged in d_out [M][D]; fully overwritten by final GEMM

    dim3 blk(256);
    dim3 gridT(D / 64, D / 64, 4);

    convert_bf16<<<dim3((unsigned)(MD / 4 / 256)), blk, 0, stream>>>(x, xbf, (int)(MD / 4));
    transpose4_bf16<<<gridT, blk, 0, stream>>>(Wz, Wx, Wdt, Wout,
                                               Wzt, Wxt, Wdtt, Woutt, D);

    // fused triple projection: grid (24, 32) = 768 blocks
    proj3_gemm<<<dim3(3 * D / GBN, M / GBM), blk, 0, stream>>>(
        xbf, Wzt, Wxt, Wdtt, bz, bx, bdt, zb, xsb, dtb, D, D);
    bc_proj<<<dim3(M / 8), blk, 0, stream>>>(x, WB, bB, WC, bC, BCb, D, M);

    // chunked scan
    dim3 gridScan(D / 256, CHUNKS, Bb);     // (4, 64, 2)
    scan_phase1<<<gridScan, blk, 0, stream>>>(xsb, dtb, BCb, A_log, Pb, Hlb, L, D, M);
    scan_phase2<<<dim3(Bb * D * N / 256), blk, 0, stream>>>(Pb, Hlb, D, N);
    scan_phase3<<<gridScan, blk, 0, stream>>>(xsb, dtb, BCb, zb, A_log, Hlb,
                                              xbf /* ybf */, L, D, M);

    // output projection
    gemm_bt<<<dim3(D / GBN, M / GBM), blk, 0, stream>>>(xbf, Woutt, bout, out, D, D);
}

// Round 14
// 168.739 us; speedup vs baseline: 1.8193x; 1.0276x over previous
//
#include <hip/hip_runtime.h>
#include <math.h>

#define CHUNKS 64
#define LCH    32    // L / CHUNKS

// m97 MFMA GEMM tile: 128x128x32, 4 waves (2x2), 64x64 per wave, double-buffered
#define GBM 128
#define GBN 128
#define GBK 32

typedef __attribute__((ext_vector_type(8))) short bf16x8;
typedef __attribute__((ext_vector_type(4))) float f32x4;
typedef __attribute__((ext_vector_type(8))) unsigned short us8;
typedef __attribute__((ext_vector_type(4))) unsigned short us4;

typedef __attribute__((address_space(1))) const unsigned int gu32;
typedef __attribute__((address_space(3))) unsigned int lu32;

__device__ __forceinline__ void gload16(const unsigned short* g, unsigned short* l) {
    // async global->LDS, 16B per lane; LDS dest = uniform base + lane*16
    __builtin_amdgcn_global_load_lds((gu32*)g, (lu32*)l, 16, 0, 0);
}

__device__ __forceinline__ unsigned short f2bf(float f) {
    unsigned int u = __float_as_uint(f);
    unsigned int r = (u + 0x7FFFu + ((u >> 16) & 1u)) >> 16;   // RNE
    return (unsigned short)r;
}

// ---------------- conversions ----------------
__global__ __launch_bounds__(256) void convert_bf16(
    const float* __restrict__ in, unsigned short* __restrict__ out, int n4)
{
    int i = blockIdx.x * 256 + threadIdx.x;
    if (i < n4) {
        float4 v = ((const float4*)in)[i];
        us4 u;
        u[0] = f2bf(v.x); u[1] = f2bf(v.y); u[2] = f2bf(v.z); u[3] = f2bf(v.w);
        ((us4*)out)[i] = u;
    }
}

// 4 weight transposes in one dispatch: W[k][n] f32 -> Wt[n][k] bf16
__global__ __launch_bounds__(256) void transpose4_bf16(
    const float* __restrict__ W0, const float* __restrict__ W1,
    const float* __restrict__ W2, const float* __restrict__ W3,
    unsigned short* __restrict__ T0, unsigned short* __restrict__ T1,
    unsigned short* __restrict__ T2, unsigned short* __restrict__ T3, int D)
{
    const float* W = (blockIdx.z == 0) ? W0 : (blockIdx.z == 1) ? W1
                   : (blockIdx.z == 2) ? W2 : W3;
    unsigned short* Wt = (blockIdx.z == 0) ? T0 : (blockIdx.z == 1) ? T1
                       : (blockIdx.z == 2) ? T2 : T3;

    __shared__ float Ls[64][65];
    const int n0 = blockIdx.x * 64;
    const int k0 = blockIdx.y * 64;
    const int tx = threadIdx.x;

#pragma unroll
    for (int i = 0; i < 4; i++) {
        int idx = tx + i * 256;
        int kr = idx >> 4;
        int ng = idx & 15;
        float4 v = *(const float4*)&W[(size_t)(k0 + kr) * D + n0 + ng * 4];
        Ls[kr][ng * 4 + 0] = v.x;
        Ls[kr][ng * 4 + 1] = v.y;
        Ls[kr][ng * 4 + 2] = v.z;
        Ls[kr][ng * 4 + 3] = v.w;
    }
    __syncthreads();
#pragma unroll
    for (int i = 0; i < 4; i++) {
        int idx = tx + i * 256;
        int nr = idx >> 4;
        int kg = idx & 15;
        us4 u;
#pragma unroll
        for (int j = 0; j < 4; j++) u[j] = f2bf(Ls[kg * 4 + j][nr]);
        *(us4*)&Wt[(size_t)(n0 + nr) * D + k0 + kg * 4] = u;
    }
}

// ---------------- m97 128x128 MFMA GEMM core, swizzled + double-buffered ----
// Staging: lane l fetches global 16B chunk q=(l&3)^((l>>3)&3) of its row;
// linear LDS dest. Read slot = lk ^ ((row>>1)&3). Bank-conflict-free
// (verified round 12: SQ_LDS_BANK_CONFLICT 1.57M -> 0).
// 2-phase pipeline: prefetch tile k+1 into the other LDS buffer BEFORE
// computing tile k; single barrier per K-step (compiler's pre-barrier
// vmcnt(0) then lands after the MFMA work, hiding the load latency).
__device__ __forceinline__ void stage_tile(
    const unsigned short* __restrict__ A, const unsigned short* __restrict__ B,
    unsigned short* As, unsigned short* Bs,
    int brow, int bcol, int K, int k0, int wave, int srow, int sq)
{
    gload16(&A[(size_t)(brow + wave * 32      + srow) * K + k0 + sq],
            &As[(wave * 32) * GBK]);
    gload16(&A[(size_t)(brow + wave * 32 + 16 + srow) * K + k0 + sq],
            &As[(wave * 32 + 16) * GBK]);
    gload16(&B[(size_t)(bcol + wave * 32      + srow) * K + k0 + sq],
            &Bs[(wave * 32) * GBK]);
    gload16(&B[(size_t)(bcol + wave * 32 + 16 + srow) * K + k0 + sq],
            &Bs[(wave * 32 + 16) * GBK]);
}

__device__ __forceinline__ void gemm_core(
    const unsigned short* __restrict__ A, const unsigned short* __restrict__ B,
    unsigned short* As, unsigned short* Bs,   // each 2 x (tile) buffers
    int brow, int bcol, int K, f32x4 acc[4][4],
    int wave, int lane, int wr, int wc, int lrow, int lk)
{
    const int srow = lane >> 2;
    const int sq   = ((lane & 3) ^ ((lane >> 3) & 3)) * 8;   // swizzled source chunk

#pragma unroll
    for (int m = 0; m < 4; m++)
#pragma unroll
        for (int n = 0; n < 4; n++) acc[m][n] = (f32x4)(0.f);

    stage_tile(A, B, As, Bs, brow, bcol, K, 0, wave, srow, sq);
    __syncthreads();

    int cur = 0;
    for (int k0 = 0; k0 < K; k0 += GBK) {
        if (k0 + GBK < K)
            stage_tile(A, B, As + (cur ^ 1) * (GBM * GBK), Bs + (cur ^ 1) * (GBN * GBK),
                       brow, bcol, K, k0 + GBK, wave, srow, sq);

        const unsigned short* as = As + cur * (GBM * GBK);
        const unsigned short* bs = Bs + cur * (GBN * GBK);

        bf16x8 av[4], bv[4];
#pragma unroll
        for (int m = 0; m < 4; m++) {
            int row = wr * 64 + m * 16 + lrow;
            av[m] = *(const bf16x8*)&as[row * GBK + ((lk ^ ((row >> 1) & 3)) * 8)];
        }
#pragma unroll
        for (int n = 0; n < 4; n++) {
            int row = wc * 64 + n * 16 + lrow;
            bv[n] = *(const bf16x8*)&bs[row * GBK + ((lk ^ ((row >> 1) & 3)) * 8)];
        }
#pragma unroll
        for (int m = 0; m < 4; m++)
#pragma unroll
            for (int n = 0; n < 4; n++)
                acc[m][n] = __builtin_amdgcn_mfma_f32_16x16x32_bf16(
                    av[m], bv[n], acc[m][n], 0, 0, 0);
        __syncthreads();   // drains prefetch (vmcnt) + lds reads (lgkmcnt)
        cur ^= 1;
    }
}

// Fused triple projection: widx = blockIdx.x>>3 selects weight/bias/act/output.
__global__ __launch_bounds__(256) void proj3_gemm(
    const unsigned short* __restrict__ A,
    const unsigned short* __restrict__ W0, const unsigned short* __restrict__ W1,
    const unsigned short* __restrict__ W2,
    const float* __restrict__ b0, const float* __restrict__ b1,
    const float* __restrict__ b2,
    float* __restrict__ o0, float* __restrict__ o1, float* __restrict__ o2,
    int K, int Nc)
{
    __shared__ unsigned short As[2 * GBM * GBK];   // 16 KB
    __shared__ unsigned short Bs[2 * GBN * GBK];   // 16 KB

    const int widx = blockIdx.x >> 3;
    const unsigned short* B = (widx == 0) ? W0 : (widx == 1) ? W1 : W2;
    const float* bias = (widx == 0) ? b0 : (widx == 1) ? b1 : b2;
    float* out = (widx == 0) ? o0 : (widx == 1) ? o1 : o2;

    const int tx = threadIdx.x;
    const int wave = tx >> 6;
    const int lane = tx & 63;
    const int wr = wave >> 1, wc = wave & 1;
    const int lrow = lane & 15, lk = lane >> 4;
    const int brow = blockIdx.y * GBM;
    const int bcol = (blockIdx.x & 7) * GBN;

    f32x4 acc[4][4];
    gemm_core(A, B, As, Bs, brow, bcol, K, acc, wave, lane, wr, wc, lrow, lk);

#pragma unroll
    for (int n = 0; n < 4; n++) {
        int col = bcol + wc * 64 + n * 16 + lrow;
        float bval = bias[col];
#pragma unroll
        for (int m = 0; m < 4; m++) {
#pragma unroll
            for (int r = 0; r < 4; r++) {
                int row = brow + wr * 64 + m * 16 + lk * 4 + r;
                float v = acc[m][n][r] + bval;
                if (widx == 0) v = 1.f / (1.f + __expf(-v));
                else if (widx == 2) v = (v > 20.f) ? v : log1pf(__expf(v));
                out[(size_t)row * Nc + col] = v;
            }
        }
    }
}

// Final GEMM (no activation)
__global__ __launch_bounds__(256) void gemm_bt(
    const unsigned short* __restrict__ A, const unsigned short* __restrict__ B,
    const float* __restrict__ bias, float* __restrict__ out, int K, int ldo)
{
    __shared__ unsigned short As[2 * GBM * GBK];
    __shared__ unsigned short Bs[2 * GBN * GBK];

    const int tx = threadIdx.x;
    const int wave = tx >> 6;
    const int lane = tx & 63;
    const int wr = wave >> 1, wc = wave & 1;
    const int lrow = lane & 15, lk = lane >> 4;
    const int brow = blockIdx.y * GBM;
    const int bcol = blockIdx.x * GBN;

    f32x4 acc[4][4];
    gemm_core(A, B, As, Bs, brow, bcol, K, acc, wave, lane, wr, wc, lrow, lk);

#pragma unroll
    for (int n = 0; n < 4; n++) {
        int col = bcol + wc * 64 + n * 16 + lrow;
        float bval = bias[col];
#pragma unroll
        for (int m = 0; m < 4; m++) {
#pragma unroll
            for (int r = 0; r < 4; r++) {
                int row = brow + wr * 64 + m * 16 + lk * 4 + r;
                out[(size_t)row * ldo + col] = acc[m][n][r] + bval;
            }
        }
    }
}

// ---------------- fused B+C projection ----------------
// BC[m][32]: cols 0..15 = Bm, 16..31 = C.
__global__ __launch_bounds__(256) void bc_proj(
    const float* __restrict__ x,
    const float* __restrict__ WB, const float* __restrict__ bB,
    const float* __restrict__ WC, const float* __restrict__ bC,
    float* __restrict__ BC, int K, int M)
{
    __shared__ unsigned short Wl[32 * 1024];   // 64 KB

    const int tx = threadIdx.x;

#pragma unroll
    for (int i = 0; i < 16; i++) {
        int e = tx + i * 256;
        int k = e >> 2;
        int n0 = (e & 3) * 4;
        float4 v = ((const float4*)WB)[e];
        float vv[4] = {v.x, v.y, v.z, v.w};
#pragma unroll
        for (int j = 0; j < 4; j++) {
            int n = n0 + j;
            Wl[n * 1024 + (((k & ~7) ^ ((n & 15) << 3)) | (k & 7))] = f2bf(vv[j]);
        }
    }
#pragma unroll
    for (int i = 0; i < 16; i++) {
        int e = tx + i * 256;
        int k = e >> 2;
        int n0 = (e & 3) * 4;
        float4 v = ((const float4*)WC)[e];
        float vv[4] = {v.x, v.y, v.z, v.w};
#pragma unroll
        for (int j = 0; j < 4; j++) {
            int n = 16 + n0 + j;
            Wl[n * 1024 + (((k & ~7) ^ ((n & 15) << 3)) | (k & 7))] = f2bf(vv[j]);
        }
    }
    __syncthreads();

    const int n = tx & 31;
    const int r = tx >> 5;
    const int row = blockIdx.x * 8 + r;

    const unsigned short* wrow = &Wl[n * 1024];
    const int sw = (n & 15) << 3;
    const float* xrow = &x[(size_t)row * K];

    float acc = 0.f;
    for (int kb = 0; kb < K; kb += 8) {
        us8 w8 = *(const us8*)&wrow[kb ^ sw];
        float4 xa = *(const float4*)&xrow[kb];
        float4 xb = *(const float4*)&xrow[kb + 4];
        float xv[8] = {xa.x, xa.y, xa.z, xa.w, xb.x, xb.y, xb.z, xb.w};
#pragma unroll
        for (int j = 0; j < 8; j++) {
            acc = fmaf(xv[j], __uint_as_float((unsigned)(unsigned short)w8[j] << 16), acc);
        }
    }

    float bias = (n < 16) ? bB[n] : bC[n - 16];
    BC[(size_t)row * 32 + n] = acc + bias;
}

// ---------------- chunked scan: thread = one d, all 16 states in regs ------
__global__ __launch_bounds__(256) void scan_phase1(
    const float* __restrict__ xs, const float* __restrict__ dt,
    const float* __restrict__ BC, const float* __restrict__ A_log,
    float* __restrict__ P, float* __restrict__ Hl, int L, int D, int M)
{
    const int tx = threadIdx.x;
    const int d  = blockIdx.x * 256 + tx;
    const int c  = blockIdx.y;
    const int b  = blockIdx.z;
    const int m0 = b * L + c * LCH;

    __shared__ float bcs[LCH][32];
    {
        int row = tx >> 3, col = (tx & 7) * 4;
        *(f32x4*)&bcs[row][col] = *(const f32x4*)&BC[(size_t)(m0 + row) * 32 + col];
    }
    __syncthreads();

    float Av[16];
#pragma unroll
    for (int i = 0; i < 4; i++) {
        f32x4 a4 = *(const f32x4*)&A_log[d * 16 + i * 4];
#pragma unroll
        for (int j = 0; j < 4; j++) Av[i * 4 + j] = -__expf(a4[j]);
    }

    float h[16];
#pragma unroll
    for (int n = 0; n < 16; n++) h[n] = 0.f;
    float dts = 0.f;

    const size_t base = (size_t)m0 * D + d;
    float dtv = dt[base], xv = xs[base];
    for (int t = 0; t < LCH; t++) {
        float dtn = 0.f, xvn = 0.f;
        if (t + 1 < LCH) {
            dtn = dt[base + (size_t)(t + 1) * D];
            xvn = xs[base + (size_t)(t + 1) * D];
        }
        float xdt = xv * dtv;
        dts += dtv;
        f32x4 bm[4];
#pragma unroll
        for (int i = 0; i < 4; i++) bm[i] = *(const f32x4*)&bcs[t][i * 4];
#pragma unroll
        for (int n = 0; n < 16; n++) {
            float a = __expf(dtv * Av[n]);
            h[n] = fmaf(a, h[n], xdt * bm[n >> 2][n & 3]);
        }
        dtv = dtn; xv = xvn;
    }

    size_t idx = (((size_t)b * D + d) * CHUNKS + c) * 16;
#pragma unroll
    for (int i = 0; i < 4; i++) {
        f32x4 p4, h4;
#pragma unroll
        for (int j = 0; j < 4; j++) {
            p4[j] = __expf(Av[i * 4 + j] * dts);
            h4[j] = h[i * 4 + j];
        }
        *(f32x4*)&P[idx + i * 4]  = p4;
        *(f32x4*)&Hl[idx + i * 4] = h4;
    }
}

__global__ __launch_bounds__(256) void scan_phase2(
    const float* __restrict__ P, float* __restrict__ Hl, int D, int N)
{
    const int tid = blockIdx.x * 256 + threadIdx.x;   // B*D*N
    const int n = tid & 15;
    const int dd = (tid >> 4) & 1023;
    const int b = tid >> 14;

    size_t base = (((size_t)b * D + dd) * CHUNKS) * 16 + n;
    float run = 0.f;
#pragma unroll 4
    for (int c = 0; c < CHUNKS; c++) {
        float p   = P[base + (size_t)c * 16];
        float tmp = Hl[base + (size_t)c * 16];
        Hl[base + (size_t)c * 16] = run;
        run = fmaf(p, run, tmp);
    }
}

__global__ __launch_bounds__(256) void scan_phase3(
    const float* __restrict__ xs, const float* __restrict__ dt,
    const float* __restrict__ BC, const float* __restrict__ z,
    const float* __restrict__ A_log, const float* __restrict__ Hin,
    unsigned short* __restrict__ ybf, int L, int D, int M)
{
    const int tx = threadIdx.x;
    const int d  = blockIdx.x * 256 + tx;
    const int c  = blockIdx.y;
    const int b  = blockIdx.z;
    const int m0 = b * L + c * LCH;

    __shared__ float bcs[LCH][32];
    {
        int row = tx >> 3, col = (tx & 7) * 4;
        *(f32x4*)&bcs[row][col] = *(const f32x4*)&BC[(size_t)(m0 + row) * 32 + col];
    }
    __syncthreads();

    float Av[16];
#pragma unroll
    for (int i = 0; i < 4; i++) {
        f32x4 a4 = *(const f32x4*)&A_log[d * 16 + i * 4];
#pragma unroll
        for (int j = 0; j < 4; j++) Av[i * 4 + j] = -__expf(a4[j]);
    }

    float h[16];
    {
        size_t hidx = (((size_t)b * D + d) * CHUNKS + c) * 16;
#pragma unroll
        for (int i = 0; i < 4; i++) {
            f32x4 h4 = *(const f32x4*)&Hin[hidx + i * 4];
#pragma unroll
            for (int j = 0; j < 4; j++) h[i * 4 + j] = h4[j];
        }
    }

    const size_t base = (size_t)m0 * D + d;
    float dtv = dt[base], xv = xs[base], zv = z[base];
    for (int t = 0; t < LCH; t++) {
        float dtn = 0.f, xvn = 0.f, zvn = 0.f;
        if (t + 1 < LCH) {
            dtn = dt[base + (size_t)(t + 1) * D];
            xvn = xs[base + (size_t)(t + 1) * D];
            zvn = z[base + (size_t)(t + 1) * D];
        }
        float xdt = xv * dtv;
        f32x4 bm[4], cm[4];
#pragma unroll
        for (int i = 0; i < 4; i++) {
            bm[i] = *(const f32x4*)&bcs[t][i * 4];
            cm[i] = *(const f32x4*)&bcs[t][16 + i * 4];
        }
        float y = 0.f;
#pragma unroll
        for (int n = 0; n < 16; n++) {
            float a = __expf(dtv * Av[n]);
            h[n] = fmaf(a, h[n], xdt * bm[n >> 2][n & 3]);
            y = fmaf(h[n], cm[n >> 2][n & 3], y);
        }
        ybf[base + (size_t)t * D] = f2bf(y * zv);
        dtv = dtn; xv = xvn; zv = zvn;
    }
}

extern "C" void kernel_launch(void* const* d_in, const int* in_sizes, int n_in,
                              void* d_out, int out_size, void* d_ws, size_t ws_size,
                              hipStream_t stream) {
    const float* x     = (const float*)d_in[0];
    const float* Wz    = (const float*)d_in[1];
    const float* bz    = (const float*)d_in[2];
    const float* Wx    = (const float*)d_in[3];
    const float* bx    = (const float*)d_in[4];
    const float* WB    = (const float*)d_in[5];
    const float* bB    = (const float*)d_in[6];
    const float* WC    = (const float*)d_in[7];
    const float* bC    = (const float*)d_in[8];
    const float* Wdt   = (const float*)d_in[9];
    const float* bdt   = (const float*)d_in[10];
    const float* A_log = (const float*)d_in[11];
    const float* Wout  = (const float*)d_in[12];
    const float* bout  = (const float*)d_in[13];
    float* out = (float*)d_out;

    const int Bb = 2, L = 2048, D = 1024, N = 16;
    const int M = Bb * L;            // 4096
    const size_t MD = (size_t)M * D; // 4M

    float* ws   = (float*)d_ws;
    float* xsb  = ws;                         // [M][D]
    float* dtb  = xsb + MD;                   // [M][D]
    float* BCb  = dtb + MD;                   // [M][32]
    float* Pb   = BCb + (size_t)M * 32;       // [B][D][CHUNKS][16]
    float* Hlb  = Pb  + (size_t)Bb * D * CHUNKS * 16;
    unsigned short* xbf   = (unsigned short*)(Hlb + (size_t)Bb * D * CHUNKS * 16);
    unsigned short* Wzt   = xbf + MD;          // xbf reused as ybf after projections
    unsigned short* Wxt   = Wzt + (size_t)D * D;
    unsigned short* Wdtt  = Wxt + (size_t)D * D;
    unsigned short* Woutt = Wdtt + (size_t)D * D;
    float* zb = out;   // z staged in d_out [M][D]; fully overwritten by final GEMM

    dim3 blk(256);
    dim3 gridT(D / 64, D / 64, 4);

    convert_bf16<<<dim3((unsigned)(MD / 4 / 256)), blk, 0, stream>>>(x, xbf, (int)(MD / 4));
    transpose4_bf16<<<gridT, blk, 0, stream>>>(Wz, Wx, Wdt, Wout,
                                               Wzt, Wxt, Wdtt, Woutt, D);

    // fused triple projection: grid (24, 32) = 768 blocks
    proj3_gemm<<<dim3(3 * D / GBN, M / GBM), blk, 0, stream>>>(
        xbf, Wzt, Wxt, Wdtt, bz, bx, bdt, zb, xsb, dtb, D, D);
    bc_proj<<<dim3(M / 8), blk, 0, stream>>>(x, WB, bB, WC, bC, BCb, D, M);

    // chunked scan
    dim3 gridScan(D / 256, CHUNKS, Bb);     // (4, 64, 2)
    scan_phase1<<<gridScan, blk, 0, stream>>>(xsb, dtb, BCb, A_log, Pb, Hlb, L, D, M);
    scan_phase2<<<dim3(Bb * D * N / 256), blk, 0, stream>>>(Pb, Hlb, D, N);
    scan_phase3<<<gridScan, blk, 0, stream>>>(xsb, dtb, BCb, zb, A_log, Hlb,
                                              xbf /* ybf */, L, D, M);

    // output projection
    gemm_bt<<<dim3(D / GBN, M / GBM), blk, 0, stream>>>(xbf, Woutt, bout, out, D, D);
}